// Round 1
// baseline (1310.850 us; speedup 1.0000x reference)
//
#include <hip/hip_runtime.h>
#include <cstdint>
#include <cstddef>

#define NN 50000
#define EE 400000
#define BN_EPS 1e-5f

// ---------------------------------------------------------------------------
// GEMM (NT): C[M x Ncol] = A[M x K] * W[Ncol x K]^T (+ optional bias)
// BM=BN=64, BK=16, 256 threads, thread computes 4x4. K%16==0, Ncol%64==0.
// ---------------------------------------------------------------------------
__global__ __launch_bounds__(256)
void gemm_nt(const float* __restrict__ A, const float* __restrict__ W,
             const float* __restrict__ bias, float* __restrict__ C,
             int M, int K, int Ncol)
{
    __shared__ __align__(16) float As[16][68];   // [k][row], pad 68 -> 16B-aligned rows
    __shared__ __align__(16) float Ws[16][68];   // [k][col]
    const int m0 = blockIdx.y * 64;
    const int n0 = blockIdx.x * 64;
    const int t  = threadIdx.x;
    const int lr = t >> 2;          // 0..63 row/col within tile for loading
    const int lc = (t & 3) * 4;     // k-quad within BK=16
    const int ty = t >> 4;          // 0..15
    const int tx = t & 15;          // 0..15
    float acc[4][4] = {{0.f,0.f,0.f,0.f},{0.f,0.f,0.f,0.f},{0.f,0.f,0.f,0.f},{0.f,0.f,0.f,0.f}};

    for (int k0 = 0; k0 < K; k0 += 16) {
        float4 av = make_float4(0.f, 0.f, 0.f, 0.f);
        const int gr = m0 + lr;
        if (gr < M) av = *(const float4*)(A + (size_t)gr * K + k0 + lc);
        const float4 wv = *(const float4*)(W + (size_t)(n0 + lr) * K + k0 + lc);
        __syncthreads();
        As[lc+0][lr] = av.x; As[lc+1][lr] = av.y; As[lc+2][lr] = av.z; As[lc+3][lr] = av.w;
        Ws[lc+0][lr] = wv.x; Ws[lc+1][lr] = wv.y; Ws[lc+2][lr] = wv.z; Ws[lc+3][lr] = wv.w;
        __syncthreads();
        #pragma unroll
        for (int kk = 0; kk < 16; ++kk) {
            const float4 a = *(const float4*)&As[kk][ty * 4];
            const float4 b = *(const float4*)&Ws[kk][tx * 4];
            acc[0][0] += a.x*b.x; acc[0][1] += a.x*b.y; acc[0][2] += a.x*b.z; acc[0][3] += a.x*b.w;
            acc[1][0] += a.y*b.x; acc[1][1] += a.y*b.y; acc[1][2] += a.y*b.z; acc[1][3] += a.y*b.w;
            acc[2][0] += a.z*b.x; acc[2][1] += a.z*b.y; acc[2][2] += a.z*b.z; acc[2][3] += a.z*b.w;
            acc[3][0] += a.w*b.x; acc[3][1] += a.w*b.y; acc[3][2] += a.w*b.z; acc[3][3] += a.w*b.w;
        }
    }
    #pragma unroll
    for (int i = 0; i < 4; ++i) {
        const int row = m0 + ty * 4 + i;
        if (row >= M) continue;
        const int col = n0 + tx * 4;
        float4 o = make_float4(acc[i][0], acc[i][1], acc[i][2], acc[i][3]);
        if (bias) { o.x += bias[col]; o.y += bias[col+1]; o.z += bias[col+2]; o.w += bias[col+3]; }
        *(float4*)(C + (size_t)row * Ncol + col) = o;
    }
}

// ---------------------------------------------------------------------------
// CSR build (dst-sorted incoming-edge lists)
// ---------------------------------------------------------------------------
__global__ void k_count(const int* __restrict__ dst, int* __restrict__ cnt)
{
    int i = blockIdx.x * blockDim.x + threadIdx.x;
    if (i < EE) atomicAdd(&cnt[dst[i]], 1);
}

__global__ __launch_bounds__(1024)
void k_scan(const int* __restrict__ cnt, int* __restrict__ offs, int N)
{
    __shared__ int buf[1024];
    __shared__ int base_s;
    const int t = threadIdx.x;
    if (t == 0) base_s = 0;
    __syncthreads();
    for (int c0 = 0; c0 < N; c0 += 1024) {
        const int i = c0 + t;
        const int v = (i < N) ? cnt[i] : 0;
        buf[t] = v;
        __syncthreads();
        for (int d = 1; d < 1024; d <<= 1) {
            int x = (t >= d) ? buf[t - d] : 0;
            __syncthreads();
            buf[t] += x;
            __syncthreads();
        }
        const int incl = buf[t];
        if (i < N) offs[i] = base_s + incl - v;   // exclusive scan
        __syncthreads();
        if (t == 1023) base_s += incl;
        __syncthreads();
    }
    if (t == 0) offs[N] = base_s;
}

__global__ void k_fill(const int* __restrict__ src, const int* __restrict__ dst,
                       const int* __restrict__ offs, int* __restrict__ fill,
                       int* __restrict__ csr)
{
    int i = blockIdx.x * blockDim.x + threadIdx.x;
    if (i < EE) {
        int d = dst[i];
        int p = offs[d] + atomicAdd(&fill[d], 1);
        csr[p] = src[i];
    }
}

// ---------------------------------------------------------------------------
// SAGE aggregation: tr[n] = mean_{s in in(n)} tl[s] + bias + tr[n]   (in-place on tr)
// block = 128 threads (one per channel), grid = NN
// ---------------------------------------------------------------------------
__global__ __launch_bounds__(128)
void k_sage_agg(const float* __restrict__ tl, float* __restrict__ tr,
                const float* __restrict__ bias, const int* __restrict__ offs,
                const int* __restrict__ csr)
{
    const int n = blockIdx.x;
    const int t = threadIdx.x;
    const int o0 = offs[n], o1 = offs[n + 1];
    const int deg = o1 - o0;
    float s = 0.f;
    for (int j = o0; j < o1; ++j) {
        const int sid = csr[j];
        s += tl[(size_t)sid * 128 + t];
    }
    const float inv = 1.f / fmaxf((float)deg, 1.f);
    const size_t idx = (size_t)n * 128 + t;
    tr[idx] = s * inv + bias[t] + tr[idx];
}

// ---------------------------------------------------------------------------
// GAT: per-node attention coefficients  asrc[n,h] = <xh[n,h,:], a_s[h]>, same adst
// block = 128 (4 heads x 32 lanes), grid = NN
// ---------------------------------------------------------------------------
__global__ __launch_bounds__(128)
void k_attn_coef(const float* __restrict__ xh, const float* __restrict__ a_s,
                 const float* __restrict__ a_d, float* __restrict__ asrc,
                 float* __restrict__ adst)
{
    const int n = blockIdx.x;
    const int t = threadIdx.x;
    const int h = t >> 5;
    const int wl = t & 31;
    float ps = 0.f, pd = 0.f;
    #pragma unroll
    for (int q = 0; q < 4; ++q) {
        const int d = wl + q * 32;
        const float v = xh[(size_t)n * 512 + h * 128 + d];
        ps += v * a_s[h * 128 + d];
        pd += v * a_d[h * 128 + d];
    }
    #pragma unroll
    for (int o = 16; o > 0; o >>= 1) {
        ps += __shfl_down(ps, o, 32);
        pd += __shfl_down(pd, o, 32);
    }
    if (wl == 0) { asrc[n * 4 + h] = ps; adst[n * 4 + h] = pd; }
}

// ---------------------------------------------------------------------------
// GAT: per-dst online softmax max+denominator over in-edges + self loop
// block = 64 (one wave), grid = NN
// ---------------------------------------------------------------------------
__global__ __launch_bounds__(64)
void k_attn_mdn(const float* __restrict__ asrc, const float* __restrict__ adst,
                const int* __restrict__ offs, const int* __restrict__ csr,
                float* __restrict__ mmax, float* __restrict__ den)
{
    const int n = blockIdx.x;
    const int l = threadIdx.x;
    const int o0 = offs[n];
    const int deg = offs[n + 1] - o0;
    const int total = deg + 1;                    // + self loop
    float ad[4];
    #pragma unroll
    for (int h = 0; h < 4; ++h) ad[h] = adst[n * 4 + h];
    float m[4], s[4];
    #pragma unroll
    for (int h = 0; h < 4; ++h) { m[h] = -3.0e38f; s[h] = 0.f; }
    for (int j = l; j < total; j += 64) {
        const int sid = (j < deg) ? csr[o0 + j] : n;
        #pragma unroll
        for (int h = 0; h < 4; ++h) {
            float e = asrc[sid * 4 + h] + ad[h];
            e = (e > 0.f) ? e : 0.2f * e;
            if (e > m[h]) { s[h] = s[h] * __expf(m[h] - e) + 1.f; m[h] = e; }
            else          { s[h] += __expf(e - m[h]); }
        }
    }
    #pragma unroll
    for (int o = 1; o < 64; o <<= 1) {
        #pragma unroll
        for (int h = 0; h < 4; ++h) {
            const float m2 = __shfl_xor(m[h], o);
            const float s2 = __shfl_xor(s[h], o);
            const float M = fmaxf(m[h], m2);
            const float sa = (s[h] != 0.f) ? s[h] * __expf(m[h] - M) : 0.f;
            const float sb = (s2   != 0.f) ? s2   * __expf(m2   - M) : 0.f;
            m[h] = M; s[h] = sa + sb;
        }
    }
    if (l == 0) {
        #pragma unroll
        for (int h = 0; h < 4; ++h) { mmax[n * 4 + h] = m[h]; den[n * 4 + h] = s[h]; }
    }
}

// ---------------------------------------------------------------------------
// GAT: weighted aggregation  out[n,c] = sum_e alpha[e,h(c)] * xh[src_e, c] + gbias[c]
// block = 64 (one wave, 8 channels/lane), grid = NN
// ---------------------------------------------------------------------------
__global__ __launch_bounds__(64)
void k_attn_agg(const float* __restrict__ xh, const float* __restrict__ asrc,
                const float* __restrict__ adst, const float* __restrict__ mmax,
                const float* __restrict__ den, const float* __restrict__ gbias,
                const int* __restrict__ offs, const int* __restrict__ csr,
                float* __restrict__ out)
{
    const int n = blockIdx.x;
    const int l = threadIdx.x;
    const int o0 = offs[n];
    const int deg = offs[n + 1] - o0;
    const int total = deg + 1;
    float ad[4], mm[4], dn[4];
    #pragma unroll
    for (int h = 0; h < 4; ++h) {
        ad[h] = adst[n * 4 + h];
        mm[h] = mmax[n * 4 + h];
        dn[h] = den[n * 4 + h];
    }
    float acc[8] = {0.f, 0.f, 0.f, 0.f, 0.f, 0.f, 0.f, 0.f};
    for (int j = 0; j < total; ++j) {
        const int sid = (j < deg) ? csr[o0 + j] : n;
        float w[4];
        #pragma unroll
        for (int h = 0; h < 4; ++h) {
            float e = asrc[sid * 4 + h] + ad[h];
            e = (e > 0.f) ? e : 0.2f * e;
            w[h] = __expf(e - mm[h]);
        }
        const float* xr = xh + (size_t)sid * 512;
        #pragma unroll
        for (int i = 0; i < 8; ++i) {
            acc[i] += w[i >> 1] * xr[l + (i << 6)];   // head = (l + 64*i) >> 7 = i>>1
        }
    }
    #pragma unroll
    for (int i = 0; i < 8; ++i) {
        const int c = l + (i << 6);
        out[(size_t)n * 512 + c] = acc[i] / dn[i >> 1] + gbias[c];
    }
}

// ---------------------------------------------------------------------------
// BatchNorm (training-mode, biased var) + ELU
// ---------------------------------------------------------------------------
__global__ void k_bn_stats(const float* __restrict__ X, float* __restrict__ sum,
                           float* __restrict__ sumsq, int C)
{
    const int c = threadIdx.x;                    // blockDim.x == C
    const int r0 = blockIdx.x * 128;
    const int r1 = min(r0 + 128, NN);
    float s = 0.f, ss = 0.f;
    for (int r = r0; r < r1; ++r) {
        const float v = X[(size_t)r * C + c];
        s += v; ss += v * v;
    }
    atomicAdd(&sum[c], s);
    atomicAdd(&sumsq[c], ss);
}

__global__ void k_bn_final(const float* __restrict__ sum, const float* __restrict__ sumsq,
                           const float* __restrict__ g, const float* __restrict__ be,
                           float* __restrict__ scale, float* __restrict__ shift, int C)
{
    const int c = threadIdx.x;
    if (c >= C) return;
    const float mean = sum[c] / (float)NN;
    float var = sumsq[c] / (float)NN - mean * mean;
    var = fmaxf(var, 0.f);
    const float sc = g[c] * rsqrtf(var + BN_EPS);
    scale[c] = sc;
    shift[c] = be[c] - mean * sc;
}

__global__ void k_bn_elu(float* __restrict__ X, const float* __restrict__ scale,
                         const float* __restrict__ shift, int C, int total)
{
    const int i = blockIdx.x * blockDim.x + threadIdx.x;
    if (i >= total) return;
    const int c = i & (C - 1);                    // C is a power of two
    const float v = X[i] * scale[c] + shift[c];
    X[i] = (v > 0.f) ? v : (__expf(v) - 1.f);
}

// ---------------------------------------------------------------------------
// Final linear: out[n, 0..1] = h4[n,:] @ Wf2^T + bf2
// ---------------------------------------------------------------------------
__global__ void k_fc2(const float* __restrict__ H, const float* __restrict__ W,
                      const float* __restrict__ bias, float* __restrict__ out)
{
    const int n = blockIdx.x * blockDim.x + threadIdx.x;
    if (n >= NN) return;
    float a0 = bias[0], a1 = bias[1];
    const float* h = H + (size_t)n * 64;
    #pragma unroll
    for (int k = 0; k < 64; ++k) {
        const float v = h[k];
        a0 += v * W[k];
        a1 += v * W[64 + k];
    }
    out[n * 2 + 0] = a0;
    out[n * 2 + 1] = a1;
}

// ---------------------------------------------------------------------------
extern "C" void kernel_launch(void* const* d_in, const int* in_sizes, int n_in,
                              void* d_out, int out_size, void* d_ws, size_t ws_size,
                              hipStream_t stream)
{
    const float* x     = (const float*)d_in[0];
    const int*   ei    = (const int*)d_in[1];
    const float* W1l   = (const float*)d_in[2];
    const float* b1    = (const float*)d_in[3];
    const float* W1r   = (const float*)d_in[4];
    const float* g1    = (const float*)d_in[5];
    const float* be1   = (const float*)d_in[6];
    const float* Wg    = (const float*)d_in[7];
    const float* a_s   = (const float*)d_in[8];
    const float* a_d   = (const float*)d_in[9];
    const float* gbias = (const float*)d_in[10];
    const float* g2    = (const float*)d_in[11];
    const float* be2   = (const float*)d_in[12];
    const float* W2l   = (const float*)d_in[13];
    const float* b2    = (const float*)d_in[14];
    const float* W2r   = (const float*)d_in[15];
    const float* g3    = (const float*)d_in[16];
    const float* be3   = (const float*)d_in[17];
    const float* Wf1   = (const float*)d_in[18];
    const float* bf1   = (const float*)d_in[19];
    const float* g4    = (const float*)d_in[20];
    const float* be4   = (const float*)d_in[21];
    const float* Wf2   = (const float*)d_in[22];
    const float* bf2   = (const float*)d_in[23];
    const int* src = ei;
    const int* dst = ei + EE;

    char* ws = (char*)d_ws;
    size_t off = 0;
    auto alloc = [&](size_t bytes) -> char* {
        char* p = ws + off;
        off += (bytes + 255) & ~(size_t)255;
        return p;
    };
    float* bufA  = (float*)alloc((size_t)NN * 128 * 4);   // tl / t2l / h4
    float* bufB  = (float*)alloc((size_t)NN * 128 * 4);   // tr / sage1 / h1
    float* bufX  = (float*)alloc((size_t)NN * 512 * 4);   // xh ; later t2r/h3
    float* bufG  = (float*)alloc((size_t)NN * 512 * 4);   // gat_out / h2
    float* asrc  = (float*)alloc((size_t)NN * 4 * 4);
    float* adst  = (float*)alloc((size_t)NN * 4 * 4);
    float* mmax  = (float*)alloc((size_t)NN * 4 * 4);
    float* den   = (float*)alloc((size_t)NN * 4 * 4);
    float* stats = (float*)alloc(2048 * 4);
    int*   cnt   = (int*)alloc((size_t)NN * 4);
    int*   offs  = (int*)alloc((size_t)(NN + 1) * 4);
    int*   fill  = (int*)alloc((size_t)NN * 4);
    int*   csr   = (int*)alloc((size_t)EE * 4);
    if (off > ws_size) return;   // workspace too small: bail without corrupting memory
    (void)in_sizes; (void)n_in; (void)out_size;

    float* sum   = stats;
    float* sumsq = stats + 512;
    float* scale = stats + 1024;
    float* shift = stats + 1536;

    // ---- CSR build ----
    hipMemsetAsync(cnt, 0, (size_t)NN * 4, stream);
    hipMemsetAsync(fill, 0, (size_t)NN * 4, stream);
    k_count<<<(EE + 255) / 256, 256, 0, stream>>>(dst, cnt);
    k_scan<<<1, 1024, 0, stream>>>(cnt, offs, NN);
    k_fill<<<(EE + 255) / 256, 256, 0, stream>>>(src, dst, offs, fill, csr);

    const int gy = (NN + 63) / 64;

    // ---- Layer 1: SAGE(256 -> 128) + BN + ELU ----
    gemm_nt<<<dim3(2, gy), 256, 0, stream>>>(x, W1l, nullptr, bufA, NN, 256, 128);
    gemm_nt<<<dim3(2, gy), 256, 0, stream>>>(x, W1r, nullptr, bufB, NN, 256, 128);
    k_sage_agg<<<NN, 128, 0, stream>>>(bufA, bufB, b1, offs, csr);
    hipMemsetAsync(sum, 0, 1024 * 4, stream);
    k_bn_stats<<<(NN + 127) / 128, 128, 0, stream>>>(bufB, sum, sumsq, 128);
    k_bn_final<<<1, 128, 0, stream>>>(sum, sumsq, g1, be1, scale, shift, 128);
    k_bn_elu<<<(NN * 128 + 255) / 256, 256, 0, stream>>>(bufB, scale, shift, 128, NN * 128);

    // ---- Layer 2: GAT(128 -> 4x128 concat) + BN + ELU ----
    gemm_nt<<<dim3(8, gy), 256, 0, stream>>>(bufB, Wg, nullptr, bufX, NN, 128, 512);
    k_attn_coef<<<NN, 128, 0, stream>>>(bufX, a_s, a_d, asrc, adst);
    k_attn_mdn<<<NN, 64, 0, stream>>>(asrc, adst, offs, csr, mmax, den);
    k_attn_agg<<<NN, 64, 0, stream>>>(bufX, asrc, adst, mmax, den, gbias, offs, csr, bufG);
    hipMemsetAsync(sum, 0, 1024 * 4, stream);
    k_bn_stats<<<(NN + 127) / 128, 512, 0, stream>>>(bufG, sum, sumsq, 512);
    k_bn_final<<<1, 512, 0, stream>>>(sum, sumsq, g2, be2, scale, shift, 512);
    k_bn_elu<<<(NN * 512 + 255) / 256, 256, 0, stream>>>(bufG, scale, shift, 512, NN * 512);

    // ---- Layer 3: SAGE(512 -> 128) + BN + ELU ----
    gemm_nt<<<dim3(2, gy), 256, 0, stream>>>(bufG, W2l, nullptr, bufA, NN, 512, 128);
    gemm_nt<<<dim3(2, gy), 256, 0, stream>>>(bufG, W2r, nullptr, bufX, NN, 512, 128);
    k_sage_agg<<<NN, 128, 0, stream>>>(bufA, bufX, b2, offs, csr);
    hipMemsetAsync(sum, 0, 1024 * 4, stream);
    k_bn_stats<<<(NN + 127) / 128, 128, 0, stream>>>(bufX, sum, sumsq, 128);
    k_bn_final<<<1, 128, 0, stream>>>(sum, sumsq, g3, be3, scale, shift, 128);
    k_bn_elu<<<(NN * 128 + 255) / 256, 256, 0, stream>>>(bufX, scale, shift, 128, NN * 128);

    // ---- Layer 4: Linear(128 -> 64) + BN + ELU ----
    gemm_nt<<<dim3(1, gy), 256, 0, stream>>>(bufX, Wf1, bf1, bufA, NN, 128, 64);
    hipMemsetAsync(sum, 0, 1024 * 4, stream);
    k_bn_stats<<<(NN + 127) / 128, 64, 0, stream>>>(bufA, sum, sumsq, 64);
    k_bn_final<<<1, 64, 0, stream>>>(sum, sumsq, g4, be4, scale, shift, 64);
    k_bn_elu<<<(NN * 64 + 255) / 256, 256, 0, stream>>>(bufA, scale, shift, 64, NN * 64);

    // ---- Layer 5: Linear(64 -> 2) ----
    k_fc2<<<(NN + 255) / 256, 256, 0, stream>>>(bufA, Wf2, bf2, (float*)d_out);
}

// Round 2
// 888.785 us; speedup vs baseline: 1.4749x; 1.4749x over previous
//
#include <hip/hip_runtime.h>
#include <cstdint>
#include <cstddef>

#define NN 50000
#define EE 400000
#define BN_EPS 1e-5f

typedef __attribute__((ext_vector_type(8))) short s16x8;
typedef __attribute__((ext_vector_type(4))) float floatx4;

// bf16 helpers (raw ushort storage, RNE rounding)
__device__ __forceinline__ unsigned short f2b(float f) {
    uint32_t u = __float_as_uint(f);
    uint32_t r = (u + 0x7fffu + ((u >> 16) & 1u)) >> 16;
    return (unsigned short)r;
}
__device__ __forceinline__ float b2f(unsigned short s) {
    return __uint_as_float((uint32_t)s << 16);
}
__device__ __forceinline__ uint32_t pack2(float a, float b) {
    return (uint32_t)f2b(a) | ((uint32_t)f2b(b) << 16);
}

#define GLD16(g, l) __builtin_amdgcn_global_load_lds(                          \
    (const __attribute__((address_space(1))) uint32_t*)(g),                    \
    (__attribute__((address_space(3))) uint32_t*)(l), 16, 0, 0)

// ---------------------------------------------------------------------------
// bf16 MFMA GEMM (NT): C[M x Ncol] = A[M x K] * W[Ncol x K]^T (+bias)
// BM=BN=128, BK=32, 256 threads = 4 waves, each wave 64x64 via 4x4 of
// mfma_f32_16x16x32_bf16. K%32==0. Ncol<=128*grid.x (clamped stage + guarded store).
// ---------------------------------------------------------------------------
template<int OBF>
__global__ __launch_bounds__(256)
void gemm_bf16mm(const unsigned short* __restrict__ A,
                 const unsigned short* __restrict__ W,
                 const float* __restrict__ bias, void* __restrict__ Cout,
                 int M, int K, int Ncol)
{
    __shared__ __align__(16) unsigned short As[128 * 32];   // [row][k] 8 KB
    __shared__ __align__(16) unsigned short Bs[128 * 32];   // [col][k] 8 KB
    const int t  = threadIdx.x;
    const int m0 = blockIdx.y * 128;
    const int n0 = blockIdx.x * 128;
    const int lane = t & 63;
    const int lr = lane & 15;            // row/col within 16-tile
    const int lq = lane >> 4;            // quad
    const int wr = (t >> 7) * 64;        // wave row base
    const int wc = ((t >> 6) & 1) * 64;  // wave col base

    floatx4 acc[4][4];
    const floatx4 zero = {0.f, 0.f, 0.f, 0.f};
    #pragma unroll
    for (int i = 0; i < 4; ++i)
        #pragma unroll
        for (int j = 0; j < 4; ++j) acc[i][j] = zero;

    for (int k0 = 0; k0 < K; k0 += 32) {
        // stage A,B tiles: 512 16B-segments each, seg = row*4 + kchunk
        #pragma unroll
        for (int it = 0; it < 2; ++it) {
            const int seg = t + it * 256;
            const int row = seg >> 2;
            const int ks  = (seg & 3) * 8;
            const unsigned short* ga = A + (size_t)min(m0 + row, M - 1) * K + k0 + ks;
            GLD16(ga, As + seg * 8);
            const unsigned short* gb = W + (size_t)min(n0 + row, Ncol - 1) * K + k0 + ks;
            GLD16(gb, Bs + seg * 8);
        }
        __syncthreads();   // drains vmcnt(0): staging complete

        s16x8 af[4], bf[4];
        #pragma unroll
        for (int i = 0; i < 4; ++i) {
            af[i] = *(const s16x8*)(As + (wr + i * 16 + lr) * 32 + lq * 8);
            bf[i] = *(const s16x8*)(Bs + (wc + i * 16 + lr) * 32 + lq * 8);
        }
        #pragma unroll
        for (int i = 0; i < 4; ++i)
            #pragma unroll
            for (int j = 0; j < 4; ++j)
                acc[i][j] = __builtin_amdgcn_mfma_f32_16x16x32_bf16(
                    af[i], bf[j], acc[i][j], 0, 0, 0);
        __syncthreads();   // LDS reads done before next stage
    }

    float* Cf = (float*)Cout;
    unsigned short* Cb = (unsigned short*)Cout;
    #pragma unroll
    for (int i = 0; i < 4; ++i) {
        #pragma unroll
        for (int j = 0; j < 4; ++j) {
            const int c = n0 + wc + j * 16 + lr;
            if (c >= Ncol) continue;
            const float bv = bias ? bias[c] : 0.f;
            #pragma unroll
            for (int r4 = 0; r4 < 4; ++r4) {
                const int r = m0 + wr + i * 16 + lq * 4 + r4;
                if (r < M) {
                    const float v = acc[i][j][r4] + bv;
                    if (OBF) Cb[(size_t)r * Ncol + c] = f2b(v);
                    else     Cf[(size_t)r * Ncol + c] = v;
                }
            }
        }
    }
}

// ---------------------------------------------------------------------------
// fp32 -> bf16 converts
// ---------------------------------------------------------------------------
__global__ void k_conv_x(const float* __restrict__ x, unsigned short* __restrict__ xb)
{
    const int i8 = (blockIdx.x * 256 + threadIdx.x) * 8;   // grid sized exactly
    const float4 f0 = *(const float4*)(x + i8);
    const float4 f1 = *(const float4*)(x + i8 + 4);
    uint4 o;
    o.x = pack2(f0.x, f0.y); o.y = pack2(f0.z, f0.w);
    o.z = pack2(f1.x, f1.y); o.w = pack2(f1.z, f1.w);
    *(uint4*)(xb + i8) = o;
}

__global__ void k_conv_w(const float* __restrict__ s0, const float* __restrict__ s1,
                         const float* __restrict__ s2, const float* __restrict__ s3,
                         const float* __restrict__ s4, const float* __restrict__ s5,
                         unsigned short* __restrict__ dst)
{
    const int i = blockIdx.x * 256 + threadIdx.x;
    if (i >= 270336) return;
    float v;
    if      (i < 32768)  v = s0[i];
    else if (i < 65536)  v = s1[i - 32768];
    else if (i < 131072) v = s2[i - 65536];
    else if (i < 196608) v = s3[i - 131072];
    else if (i < 262144) v = s4[i - 196608];
    else                 v = s5[i - 262144];
    dst[i] = f2b(v);
}

// ---------------------------------------------------------------------------
// CSR build (dst-sorted incoming-edge lists)
// ---------------------------------------------------------------------------
__global__ void k_count(const int* __restrict__ dst, int* __restrict__ cnt)
{
    int i = blockIdx.x * blockDim.x + threadIdx.x;
    if (i < EE) atomicAdd(&cnt[dst[i]], 1);
}

__global__ __launch_bounds__(1024)
void k_scan(const int* __restrict__ cnt, int* __restrict__ offs, int N)
{
    __shared__ int buf[1024];
    __shared__ int base_s;
    const int t = threadIdx.x;
    if (t == 0) base_s = 0;
    __syncthreads();
    for (int c0 = 0; c0 < N; c0 += 1024) {
        const int i = c0 + t;
        const int v = (i < N) ? cnt[i] : 0;
        buf[t] = v;
        __syncthreads();
        for (int d = 1; d < 1024; d <<= 1) {
            int x = (t >= d) ? buf[t - d] : 0;
            __syncthreads();
            buf[t] += x;
            __syncthreads();
        }
        const int incl = buf[t];
        if (i < N) offs[i] = base_s + incl - v;
        __syncthreads();
        if (t == 1023) base_s += incl;
        __syncthreads();
    }
    if (t == 0) offs[N] = base_s;
}

__global__ void k_fill(const int* __restrict__ src, const int* __restrict__ dst,
                       const int* __restrict__ offs, int* __restrict__ fill,
                       int* __restrict__ csr)
{
    int i = blockIdx.x * blockDim.x + threadIdx.x;
    if (i < EE) {
        int d = dst[i];
        int p = offs[d] + atomicAdd(&fill[d], 1);
        csr[p] = src[i];
    }
}

// ---------------------------------------------------------------------------
// SAGE aggregation: tr[n] = mean_{s in in(n)} tl_b[s] + bias + tr[n]
// ---------------------------------------------------------------------------
__global__ __launch_bounds__(128)
void k_sage_agg(const unsigned short* __restrict__ tl, float* __restrict__ tr,
                const float* __restrict__ bias, const int* __restrict__ offs,
                const int* __restrict__ csr)
{
    const int n = blockIdx.x;
    const int t = threadIdx.x;
    const int o0 = offs[n], o1 = offs[n + 1];
    const int deg = o1 - o0;
    float s = 0.f;
    for (int j = o0; j < o1; ++j) {
        const int sid = csr[j];
        s += b2f(tl[(size_t)sid * 128 + t]);
    }
    const float inv = 1.f / fmaxf((float)deg, 1.f);
    const size_t idx = (size_t)n * 128 + t;
    tr[idx] = s * inv + bias[t] + tr[idx];
}

// ---------------------------------------------------------------------------
// GAT per-node coefficients: one wave per node, lane covers 8 channels
// ---------------------------------------------------------------------------
__global__ __launch_bounds__(64)
void k_attn_coef(const unsigned short* __restrict__ xh, const float* __restrict__ a_s,
                 const float* __restrict__ a_d, float* __restrict__ asrc,
                 float* __restrict__ adst)
{
    const int n = blockIdx.x;
    const int l = threadIdx.x;
    const int c0 = l * 8;
    const int h = l >> 4;
    const uint4 q = *(const uint4*)(xh + (size_t)n * 512 + c0);
    float v[8];
    v[0] = __uint_as_float(q.x << 16); v[1] = __uint_as_float(q.x & 0xffff0000u);
    v[2] = __uint_as_float(q.y << 16); v[3] = __uint_as_float(q.y & 0xffff0000u);
    v[4] = __uint_as_float(q.z << 16); v[5] = __uint_as_float(q.z & 0xffff0000u);
    v[6] = __uint_as_float(q.w << 16); v[7] = __uint_as_float(q.w & 0xffff0000u);
    float ps = 0.f, pd = 0.f;
    #pragma unroll
    for (int i = 0; i < 8; ++i) {
        ps += v[i] * a_s[c0 + i];
        pd += v[i] * a_d[c0 + i];
    }
    #pragma unroll
    for (int o = 1; o < 16; o <<= 1) {
        ps += __shfl_xor(ps, o);
        pd += __shfl_xor(pd, o);
    }
    if ((l & 15) == 0) { asrc[n * 4 + h] = ps; adst[n * 4 + h] = pd; }
}

// ---------------------------------------------------------------------------
// GAT per-dst online softmax (max + denominator), self-loop included
// ---------------------------------------------------------------------------
__global__ __launch_bounds__(64)
void k_attn_mdn(const float* __restrict__ asrc, const float* __restrict__ adst,
                const int* __restrict__ offs, const int* __restrict__ csr,
                float* __restrict__ mmax, float* __restrict__ den)
{
    const int n = blockIdx.x;
    const int l = threadIdx.x;
    const int o0 = offs[n];
    const int deg = offs[n + 1] - o0;
    const int total = deg + 1;
    float ad[4];
    #pragma unroll
    for (int h = 0; h < 4; ++h) ad[h] = adst[n * 4 + h];
    float m[4], s[4];
    #pragma unroll
    for (int h = 0; h < 4; ++h) { m[h] = -3.0e38f; s[h] = 0.f; }
    for (int j = l; j < total; j += 64) {
        const int sid = (j < deg) ? csr[o0 + j] : n;
        #pragma unroll
        for (int h = 0; h < 4; ++h) {
            float e = asrc[sid * 4 + h] + ad[h];
            e = (e > 0.f) ? e : 0.2f * e;
            if (e > m[h]) { s[h] = s[h] * __expf(m[h] - e) + 1.f; m[h] = e; }
            else          { s[h] += __expf(e - m[h]); }
        }
    }
    #pragma unroll
    for (int o = 1; o < 64; o <<= 1) {
        #pragma unroll
        for (int h = 0; h < 4; ++h) {
            const float m2 = __shfl_xor(m[h], o);
            const float s2 = __shfl_xor(s[h], o);
            const float M = fmaxf(m[h], m2);
            const float sa = (s[h] != 0.f) ? s[h] * __expf(m[h] - M) : 0.f;
            const float sb = (s2   != 0.f) ? s2   * __expf(m2   - M) : 0.f;
            m[h] = M; s[h] = sa + sb;
        }
    }
    if (l == 0) {
        #pragma unroll
        for (int h = 0; h < 4; ++h) { mmax[n * 4 + h] = m[h]; den[n * 4 + h] = s[h]; }
    }
}

// ---------------------------------------------------------------------------
// GAT weighted aggregation: bf16 xh gather, bf16 out (+gbias)
// one wave per node; lane covers 8 consecutive channels (one head)
// ---------------------------------------------------------------------------
__global__ __launch_bounds__(64)
void k_attn_agg(const unsigned short* __restrict__ xh, const float* __restrict__ asrc,
                const float* __restrict__ adst, const float* __restrict__ mmax,
                const float* __restrict__ den, const float* __restrict__ gbias,
                const int* __restrict__ offs, const int* __restrict__ csr,
                unsigned short* __restrict__ out)
{
    const int n = blockIdx.x;
    const int l = threadIdx.x;
    const int c0 = l * 8;
    const int h = l >> 4;
    const int o0 = offs[n];
    const int deg = offs[n + 1] - o0;
    const int total = deg + 1;
    const float ad = adst[n * 4 + h];
    const float mm = mmax[n * 4 + h];
    const float dn = den[n * 4 + h];
    float acc[8] = {0.f, 0.f, 0.f, 0.f, 0.f, 0.f, 0.f, 0.f};
    for (int j = 0; j < total; ++j) {
        const int sid = (j < deg) ? csr[o0 + j] : n;
        float e = asrc[sid * 4 + h] + ad;
        e = (e > 0.f) ? e : 0.2f * e;
        const float w = __expf(e - mm);
        const uint4 q = *(const uint4*)(xh + (size_t)sid * 512 + c0);
        acc[0] += w * __uint_as_float(q.x << 16);
        acc[1] += w * __uint_as_float(q.x & 0xffff0000u);
        acc[2] += w * __uint_as_float(q.y << 16);
        acc[3] += w * __uint_as_float(q.y & 0xffff0000u);
        acc[4] += w * __uint_as_float(q.z << 16);
        acc[5] += w * __uint_as_float(q.z & 0xffff0000u);
        acc[6] += w * __uint_as_float(q.w << 16);
        acc[7] += w * __uint_as_float(q.w & 0xffff0000u);
    }
    const float r = 1.f / dn;
    float o[8];
    #pragma unroll
    for (int i = 0; i < 8; ++i) o[i] = acc[i] * r + gbias[c0 + i];
    uint4 ov;
    ov.x = pack2(o[0], o[1]); ov.y = pack2(o[2], o[3]);
    ov.z = pack2(o[4], o[5]); ov.w = pack2(o[6], o[7]);
    *(uint4*)(out + (size_t)n * 512 + c0) = ov;
}

// ---------------------------------------------------------------------------
// BatchNorm (training-mode, biased var) + ELU
// ---------------------------------------------------------------------------
__global__ void k_bn_stats_f(const float* __restrict__ X, float* __restrict__ sum,
                             float* __restrict__ sumsq, int C)
{
    const int c = threadIdx.x;
    const int r0 = blockIdx.x * 128;
    const int r1 = min(r0 + 128, NN);
    float s = 0.f, ss = 0.f;
    for (int r = r0; r < r1; ++r) {
        const float v = X[(size_t)r * C + c];
        s += v; ss += v * v;
    }
    atomicAdd(&sum[c], s);
    atomicAdd(&sumsq[c], ss);
}

__global__ void k_bn_stats_b(const unsigned short* __restrict__ X, float* __restrict__ sum,
                             float* __restrict__ sumsq, int C)
{
    const int c = threadIdx.x;
    const int r0 = blockIdx.x * 128;
    const int r1 = min(r0 + 128, NN);
    float s = 0.f, ss = 0.f;
    for (int r = r0; r < r1; ++r) {
        const float v = b2f(X[(size_t)r * C + c]);
        s += v; ss += v * v;
    }
    atomicAdd(&sum[c], s);
    atomicAdd(&sumsq[c], ss);
}

__global__ void k_bn_final(const float* __restrict__ sum, const float* __restrict__ sumsq,
                           const float* __restrict__ g, const float* __restrict__ be,
                           float* __restrict__ scale, float* __restrict__ shift, int C)
{
    const int c = threadIdx.x;
    if (c >= C) return;
    const float mean = sum[c] / (float)NN;
    float var = sumsq[c] / (float)NN - mean * mean;
    var = fmaxf(var, 0.f);
    const float sc = g[c] * rsqrtf(var + BN_EPS);
    scale[c] = sc;
    shift[c] = be[c] - mean * sc;
}

// fp32 in -> bf16 out (separate dst)
__global__ void k_bn_elu_f2b(const float* __restrict__ X, unsigned short* __restrict__ D,
                             const float* __restrict__ scale, const float* __restrict__ shift,
                             int C, int total)
{
    const int i = blockIdx.x * blockDim.x + threadIdx.x;
    if (i >= total) return;
    const int c = i & (C - 1);
    const float v = X[i] * scale[c] + shift[c];
    D[i] = f2b((v > 0.f) ? v : (__expf(v) - 1.f));
}

// bf16 in-place
__global__ void k_bn_elu_b2b(unsigned short* __restrict__ X,
                             const float* __restrict__ scale, const float* __restrict__ shift,
                             int C, int total)
{
    const int i = blockIdx.x * blockDim.x + threadIdx.x;
    if (i >= total) return;
    const int c = i & (C - 1);
    const float v = b2f(X[i]) * scale[c] + shift[c];
    X[i] = f2b((v > 0.f) ? v : (__expf(v) - 1.f));
}

// fp32 in-place
__global__ void k_bn_elu_f32(float* __restrict__ X,
                             const float* __restrict__ scale, const float* __restrict__ shift,
                             int C, int total)
{
    const int i = blockIdx.x * blockDim.x + threadIdx.x;
    if (i >= total) return;
    const int c = i & (C - 1);
    const float v = X[i] * scale[c] + shift[c];
    X[i] = (v > 0.f) ? v : (__expf(v) - 1.f);
}

// ---------------------------------------------------------------------------
// Final linear: out[n, 0..1] = h4[n,:] @ Wf2^T + bf2
// ---------------------------------------------------------------------------
__global__ void k_fc2(const float* __restrict__ H, const float* __restrict__ W,
                      const float* __restrict__ bias, float* __restrict__ out)
{
    const int n = blockIdx.x * blockDim.x + threadIdx.x;
    if (n >= NN) return;
    float a0 = bias[0], a1 = bias[1];
    const float* h = H + (size_t)n * 64;
    #pragma unroll
    for (int k = 0; k < 64; ++k) {
        const float v = h[k];
        a0 += v * W[k];
        a1 += v * W[64 + k];
    }
    out[n * 2 + 0] = a0;
    out[n * 2 + 1] = a1;
}

// ---------------------------------------------------------------------------
extern "C" void kernel_launch(void* const* d_in, const int* in_sizes, int n_in,
                              void* d_out, int out_size, void* d_ws, size_t ws_size,
                              hipStream_t stream)
{
    const float* x     = (const float*)d_in[0];
    const int*   ei    = (const int*)d_in[1];
    const float* W1l   = (const float*)d_in[2];
    const float* b1    = (const float*)d_in[3];
    const float* W1r   = (const float*)d_in[4];
    const float* g1    = (const float*)d_in[5];
    const float* be1   = (const float*)d_in[6];
    const float* Wg    = (const float*)d_in[7];
    const float* a_s   = (const float*)d_in[8];
    const float* a_d   = (const float*)d_in[9];
    const float* gbias = (const float*)d_in[10];
    const float* g2    = (const float*)d_in[11];
    const float* be2   = (const float*)d_in[12];
    const float* W2l   = (const float*)d_in[13];
    const float* b2    = (const float*)d_in[14];
    const float* W2r   = (const float*)d_in[15];
    const float* g3    = (const float*)d_in[16];
    const float* be3   = (const float*)d_in[17];
    const float* Wf1   = (const float*)d_in[18];
    const float* bf1   = (const float*)d_in[19];
    const float* g4    = (const float*)d_in[20];
    const float* be4   = (const float*)d_in[21];
    const float* Wf2   = (const float*)d_in[22];
    const float* bf2   = (const float*)d_in[23];
    const int* src = ei;
    const int* dst = ei + EE;

    char* ws = (char*)d_ws;
    size_t off = 0;
    auto alloc = [&](size_t bytes) -> char* {
        char* p = ws + off;
        off += (bytes + 255) & ~(size_t)255;
        return p;
    };
    unsigned short* xb   = (unsigned short*)alloc((size_t)NN * 256 * 2);  // 25.6 MB
    unsigned short* waren= (unsigned short*)alloc(270336 * 2);
    unsigned short* tlb  = (unsigned short*)alloc((size_t)NN * 128 * 2);  // tl / t2l
    float*          trF  = (float*)alloc((size_t)NN * 128 * 4);           // tr / t2r / h4
    unsigned short* h1b  = (unsigned short*)alloc((size_t)NN * 128 * 2);  // h1 / h3
    unsigned short* xhb  = (unsigned short*)alloc((size_t)NN * 512 * 2);  // 51.2 MB
    unsigned short* gatb = (unsigned short*)alloc((size_t)NN * 512 * 2);  // gat_out / h2
    float* asrc  = (float*)alloc((size_t)NN * 4 * 4);
    float* adst  = (float*)alloc((size_t)NN * 4 * 4);
    float* mmax  = (float*)alloc((size_t)NN * 4 * 4);
    float* den   = (float*)alloc((size_t)NN * 4 * 4);
    float* stats = (float*)alloc(2048 * 4);
    int*   cnt   = (int*)alloc((size_t)NN * 4);
    int*   offs  = (int*)alloc((size_t)(NN + 1) * 4);
    int*   fill  = (int*)alloc((size_t)NN * 4);
    int*   csr   = (int*)alloc((size_t)EE * 4);
    if (off > ws_size) return;
    (void)in_sizes; (void)n_in; (void)out_size;

    unsigned short* W1l_b = waren;
    unsigned short* W1r_b = waren + 32768;
    unsigned short* Wg_b  = waren + 65536;
    unsigned short* W2l_b = waren + 131072;
    unsigned short* W2r_b = waren + 196608;
    unsigned short* Wf1_b = waren + 262144;

    float* sum   = stats;
    float* sumsq = stats + 512;
    float* scale = stats + 1024;
    float* shift = stats + 1536;

    // ---- converts + CSR build ----
    k_conv_x<<<6250, 256, 0, stream>>>(x, xb);                       // 50000*256/2048
    k_conv_w<<<1056, 256, 0, stream>>>(W1l, W1r, Wg, W2l, W2r, Wf1, waren);
    hipMemsetAsync(cnt, 0, (size_t)NN * 4, stream);
    hipMemsetAsync(fill, 0, (size_t)NN * 4, stream);
    k_count<<<(EE + 255) / 256, 256, 0, stream>>>(dst, cnt);
    k_scan<<<1, 1024, 0, stream>>>(cnt, offs, NN);
    k_fill<<<(EE + 255) / 256, 256, 0, stream>>>(src, dst, offs, fill, csr);

    const int gy = (NN + 127) / 128;   // 391

    // ---- Layer 1: SAGE(256 -> 128) + BN + ELU ----
    gemm_bf16mm<1><<<dim3(1, gy), 256, 0, stream>>>(xb, W1l_b, nullptr, tlb, NN, 256, 128);
    gemm_bf16mm<0><<<dim3(1, gy), 256, 0, stream>>>(xb, W1r_b, nullptr, trF, NN, 256, 128);
    k_sage_agg<<<NN, 128, 0, stream>>>(tlb, trF, b1, offs, csr);
    hipMemsetAsync(sum, 0, 1024 * 4, stream);
    k_bn_stats_f<<<gy, 128, 0, stream>>>(trF, sum, sumsq, 128);
    k_bn_final<<<1, 128, 0, stream>>>(sum, sumsq, g1, be1, scale, shift, 128);
    k_bn_elu_f2b<<<(NN * 128 + 255) / 256, 256, 0, stream>>>(trF, h1b, scale, shift, 128, NN * 128);

    // ---- Layer 2: GAT(128 -> 4x128) + BN + ELU ----
    gemm_bf16mm<1><<<dim3(4, gy), 256, 0, stream>>>(h1b, Wg_b, nullptr, xhb, NN, 128, 512);
    k_attn_coef<<<NN, 64, 0, stream>>>(xhb, a_s, a_d, asrc, adst);
    k_attn_mdn<<<NN, 64, 0, stream>>>(asrc, adst, offs, csr, mmax, den);
    k_attn_agg<<<NN, 64, 0, stream>>>(xhb, asrc, adst, mmax, den, gbias, offs, csr, gatb);
    hipMemsetAsync(sum, 0, 1024 * 4, stream);
    k_bn_stats_b<<<gy, 512, 0, stream>>>(gatb, sum, sumsq, 512);
    k_bn_final<<<1, 512, 0, stream>>>(sum, sumsq, g2, be2, scale, shift, 512);
    k_bn_elu_b2b<<<(NN * 512 + 255) / 256, 256, 0, stream>>>(gatb, scale, shift, 512, NN * 512);

    // ---- Layer 3: SAGE(512 -> 128) + BN + ELU ----
    gemm_bf16mm<1><<<dim3(1, gy), 256, 0, stream>>>(gatb, W2l_b, nullptr, tlb, NN, 512, 128);
    gemm_bf16mm<0><<<dim3(1, gy), 256, 0, stream>>>(gatb, W2r_b, nullptr, trF, NN, 512, 128);
    k_sage_agg<<<NN, 128, 0, stream>>>(tlb, trF, b2, offs, csr);
    hipMemsetAsync(sum, 0, 1024 * 4, stream);
    k_bn_stats_f<<<gy, 128, 0, stream>>>(trF, sum, sumsq, 128);
    k_bn_final<<<1, 128, 0, stream>>>(sum, sumsq, g3, be3, scale, shift, 128);
    k_bn_elu_f2b<<<(NN * 128 + 255) / 256, 256, 0, stream>>>(trF, h1b, scale, shift, 128, NN * 128);

    // ---- Layer 4: Linear(128 -> 64) + BN + ELU ----
    gemm_bf16mm<0><<<dim3(1, gy), 256, 0, stream>>>(h1b, Wf1_b, bf1, trF, NN, 128, 64);
    hipMemsetAsync(sum, 0, 1024 * 4, stream);
    k_bn_stats_f<<<gy, 64, 0, stream>>>(trF, sum, sumsq, 64);
    k_bn_final<<<1, 64, 0, stream>>>(sum, sumsq, g4, be4, scale, shift, 64);
    k_bn_elu_f32<<<(NN * 64 + 255) / 256, 256, 0, stream>>>(trF, scale, shift, 64, NN * 64);

    // ---- Layer 5: Linear(64 -> 2) ----
    k_fc2<<<(NN + 255) / 256, 256, 0, stream>>>(trF, Wf2, bf2, (float*)d_out);
}

// Round 3
// 804.580 us; speedup vs baseline: 1.6292x; 1.1047x over previous
//
#include <hip/hip_runtime.h>
#include <cstdint>
#include <cstddef>

#define NN 50000
#define EE 400000
#define BN_EPS 1e-5f
#define NB_SCAN 196   // ceil(50000/256)

typedef __attribute__((ext_vector_type(8))) short s16x8;
typedef __attribute__((ext_vector_type(4))) float floatx4;

// bf16 helpers (raw ushort storage, RNE rounding)
__device__ __forceinline__ unsigned short f2b(float f) {
    uint32_t u = __float_as_uint(f);
    uint32_t r = (u + 0x7fffu + ((u >> 16) & 1u)) >> 16;
    return (unsigned short)r;
}
__device__ __forceinline__ float b2f(unsigned short s) {
    return __uint_as_float((uint32_t)s << 16);
}
__device__ __forceinline__ uint32_t pack2(float a, float b) {
    return (uint32_t)f2b(a) | ((uint32_t)f2b(b) << 16);
}

#define GLD16(g, l) __builtin_amdgcn_global_load_lds(                          \
    (const __attribute__((address_space(1))) uint32_t*)(g),                    \
    (__attribute__((address_space(3))) uint32_t*)(l), 16, 0, 0)

// ---------------------------------------------------------------------------
// bf16 MFMA GEMM (NT): C[M x Ncol] = A[M x K] * W[Ncol x K]^T (+bias)
// BM=BN=128, BK=32, 256 threads = 4 waves, each wave 64x64 via 4x4 of
// mfma_f32_16x16x32_bf16. K%32==0.
// ---------------------------------------------------------------------------
template<int OBF>
__global__ __launch_bounds__(256)
void gemm_bf16mm(const unsigned short* __restrict__ A,
                 const unsigned short* __restrict__ W,
                 const float* __restrict__ bias, void* __restrict__ Cout,
                 int M, int K, int Ncol)
{
    __shared__ __align__(16) unsigned short As[128 * 32];   // [row][k] 8 KB
    __shared__ __align__(16) unsigned short Bs[128 * 32];   // [col][k] 8 KB
    const int t  = threadIdx.x;
    const int m0 = blockIdx.y * 128;
    const int n0 = blockIdx.x * 128;
    const int lane = t & 63;
    const int lr = lane & 15;            // row/col within 16-tile
    const int lq = lane >> 4;            // quad
    const int wr = (t >> 7) * 64;        // wave row base
    const int wc = ((t >> 6) & 1) * 64;  // wave col base

    floatx4 acc[4][4];
    const floatx4 zero = {0.f, 0.f, 0.f, 0.f};
    #pragma unroll
    for (int i = 0; i < 4; ++i)
        #pragma unroll
        for (int j = 0; j < 4; ++j) acc[i][j] = zero;

    for (int k0 = 0; k0 < K; k0 += 32) {
        #pragma unroll
        for (int it = 0; it < 2; ++it) {
            const int seg = t + it * 256;
            const int row = seg >> 2;
            const int ks  = (seg & 3) * 8;
            const unsigned short* ga = A + (size_t)min(m0 + row, M - 1) * K + k0 + ks;
            GLD16(ga, As + seg * 8);
            const unsigned short* gb = W + (size_t)min(n0 + row, Ncol - 1) * K + k0 + ks;
            GLD16(gb, Bs + seg * 8);
        }
        __syncthreads();

        s16x8 af[4], bf[4];
        #pragma unroll
        for (int i = 0; i < 4; ++i) {
            af[i] = *(const s16x8*)(As + (wr + i * 16 + lr) * 32 + lq * 8);
            bf[i] = *(const s16x8*)(Bs + (wc + i * 16 + lr) * 32 + lq * 8);
        }
        #pragma unroll
        for (int i = 0; i < 4; ++i)
            #pragma unroll
            for (int j = 0; j < 4; ++j)
                acc[i][j] = __builtin_amdgcn_mfma_f32_16x16x32_bf16(
                    af[i], bf[j], acc[i][j], 0, 0, 0);
        __syncthreads();
    }

    float* Cf = (float*)Cout;
    unsigned short* Cb = (unsigned short*)Cout;
    #pragma unroll
    for (int i = 0; i < 4; ++i) {
        #pragma unroll
        for (int j = 0; j < 4; ++j) {
            const int c = n0 + wc + j * 16 + lr;
            if (c >= Ncol) continue;
            const float bv = bias ? bias[c] : 0.f;
            #pragma unroll
            for (int r4 = 0; r4 < 4; ++r4) {
                const int r = m0 + wr + i * 16 + lq * 4 + r4;
                if (r < M) {
                    const float v = acc[i][j][r4] + bv;
                    if (OBF) Cb[(size_t)r * Ncol + c] = f2b(v);
                    else     Cf[(size_t)r * Ncol + c] = v;
                }
            }
        }
    }
}

// ---------------------------------------------------------------------------
// fp32 -> bf16 converts
// ---------------------------------------------------------------------------
__global__ void k_conv_x(const float* __restrict__ x, unsigned short* __restrict__ xb)
{
    const int i8 = (blockIdx.x * 256 + threadIdx.x) * 8;
    const float4 f0 = *(const float4*)(x + i8);
    const float4 f1 = *(const float4*)(x + i8 + 4);
    uint4 o;
    o.x = pack2(f0.x, f0.y); o.y = pack2(f0.z, f0.w);
    o.z = pack2(f1.x, f1.y); o.w = pack2(f1.z, f1.w);
    *(uint4*)(xb + i8) = o;
}

__global__ void k_conv_w(const float* __restrict__ s0, const float* __restrict__ s1,
                         const float* __restrict__ s2, const float* __restrict__ s3,
                         const float* __restrict__ s4, const float* __restrict__ s5,
                         unsigned short* __restrict__ dst)
{
    const int i = blockIdx.x * 256 + threadIdx.x;
    if (i >= 270336) return;
    float v;
    if      (i < 32768)  v = s0[i];
    else if (i < 65536)  v = s1[i - 32768];
    else if (i < 131072) v = s2[i - 65536];
    else if (i < 196608) v = s3[i - 131072];
    else if (i < 262144) v = s4[i - 196608];
    else                 v = s5[i - 262144];
    dst[i] = f2b(v);
}

// ---------------------------------------------------------------------------
// CSR build: count -> multi-block exclusive scan -> fill
// ---------------------------------------------------------------------------
__global__ void k_count(const int* __restrict__ dst, int* __restrict__ cnt)
{
    int i = blockIdx.x * blockDim.x + threadIdx.x;
    if (i < EE) atomicAdd(&cnt[dst[i]], 1);
}

__global__ __launch_bounds__(256)
void k_scan_blk(const int* __restrict__ cnt, int* __restrict__ offs,
                int* __restrict__ bsum, int N)
{
    __shared__ int wsum[4];
    const int t = threadIdx.x;
    const int i = blockIdx.x * 256 + t;
    const int v = (i < N) ? cnt[i] : 0;
    int s = v;
    #pragma unroll
    for (int o = 1; o < 64; o <<= 1) {
        const int u = __shfl_up(s, o);
        if ((t & 63) >= o) s += u;
    }
    const int wid = t >> 6;
    if ((t & 63) == 63) wsum[wid] = s;
    __syncthreads();
    int base = 0;
    #pragma unroll
    for (int w = 0; w < 3; ++w) if (w < wid) base += wsum[w];
    if (i < N) offs[i] = base + s - v;      // block-local exclusive
    if (t == 255) bsum[blockIdx.x] = base + s;
}

__global__ __launch_bounds__(256)
void k_scan_top(int* __restrict__ bsum, int* __restrict__ offs, int N)
{
    __shared__ int wsum[4];
    const int t = threadIdx.x;
    const int v = (t < NB_SCAN) ? bsum[t] : 0;
    int s = v;
    #pragma unroll
    for (int o = 1; o < 64; o <<= 1) {
        const int u = __shfl_up(s, o);
        if ((t & 63) >= o) s += u;
    }
    const int wid = t >> 6;
    if ((t & 63) == 63) wsum[wid] = s;
    __syncthreads();
    int base = 0;
    #pragma unroll
    for (int w = 0; w < 3; ++w) if (w < wid) base += wsum[w];
    if (t < NB_SCAN) bsum[t] = base + s - v;   // exclusive block base
    if (t == 255) offs[N] = base + s;          // grand total (== EE)
}

__global__ __launch_bounds__(256)
void k_scan_add(int* __restrict__ offs, const int* __restrict__ bsum, int N)
{
    const int i = blockIdx.x * 256 + threadIdx.x;
    if (i < N) offs[i] += bsum[blockIdx.x];
}

__global__ void k_fill(const int* __restrict__ src, const int* __restrict__ dst,
                       const int* __restrict__ offs, int* __restrict__ fill,
                       int* __restrict__ csr)
{
    int i = blockIdx.x * blockDim.x + threadIdx.x;
    if (i < EE) {
        int d = dst[i];
        int p = offs[d] + atomicAdd(&fill[d], 1);
        csr[p] = src[i];
    }
}

// ---------------------------------------------------------------------------
// SAGE aggregation: tr[n] = mean_{s in in(n)} tl_b[s] + bias + tr[n]
// ---------------------------------------------------------------------------
__global__ __launch_bounds__(128)
void k_sage_agg(const unsigned short* __restrict__ tl, float* __restrict__ tr,
                const float* __restrict__ bias, const int* __restrict__ offs,
                const int* __restrict__ csr)
{
    const int n = blockIdx.x;
    const int t = threadIdx.x;
    const int o0 = offs[n], o1 = offs[n + 1];
    const int deg = o1 - o0;
    float s = 0.f;
    for (int j = o0; j < o1; ++j) {
        const int sid = csr[j];
        s += b2f(tl[(size_t)sid * 128 + t]);
    }
    const float inv = 1.f / fmaxf((float)deg, 1.f);
    const size_t idx = (size_t)n * 128 + t;
    tr[idx] = s * inv + bias[t] + tr[idx];
}

// ---------------------------------------------------------------------------
// GAT per-node coefficients
// ---------------------------------------------------------------------------
__global__ __launch_bounds__(64)
void k_attn_coef(const unsigned short* __restrict__ xh, const float* __restrict__ a_s,
                 const float* __restrict__ a_d, float* __restrict__ asrc,
                 float* __restrict__ adst)
{
    const int n = blockIdx.x;
    const int l = threadIdx.x;
    const int c0 = l * 8;
    const int h = l >> 4;
    const uint4 q = *(const uint4*)(xh + (size_t)n * 512 + c0);
    float v[8];
    v[0] = __uint_as_float(q.x << 16); v[1] = __uint_as_float(q.x & 0xffff0000u);
    v[2] = __uint_as_float(q.y << 16); v[3] = __uint_as_float(q.y & 0xffff0000u);
    v[4] = __uint_as_float(q.z << 16); v[5] = __uint_as_float(q.z & 0xffff0000u);
    v[6] = __uint_as_float(q.w << 16); v[7] = __uint_as_float(q.w & 0xffff0000u);
    float ps = 0.f, pd = 0.f;
    #pragma unroll
    for (int i = 0; i < 8; ++i) {
        ps += v[i] * a_s[c0 + i];
        pd += v[i] * a_d[c0 + i];
    }
    #pragma unroll
    for (int o = 1; o < 16; o <<= 1) {
        ps += __shfl_xor(ps, o);
        pd += __shfl_xor(pd, o);
    }
    if ((l & 15) == 0) { asrc[n * 4 + h] = ps; adst[n * 4 + h] = pd; }
}

// ---------------------------------------------------------------------------
// GAT per-dst online softmax (max + denominator), self-loop included
// ---------------------------------------------------------------------------
__global__ __launch_bounds__(64)
void k_attn_mdn(const float* __restrict__ asrc, const float* __restrict__ adst,
                const int* __restrict__ offs, const int* __restrict__ csr,
                float* __restrict__ mmax, float* __restrict__ den)
{
    const int n = blockIdx.x;
    const int l = threadIdx.x;
    const int o0 = offs[n];
    const int deg = offs[n + 1] - o0;
    const int total = deg + 1;
    const float4 adv = *(const float4*)(adst + n * 4);
    const float ad[4] = {adv.x, adv.y, adv.z, adv.w};
    float m[4], s[4];
    #pragma unroll
    for (int h = 0; h < 4; ++h) { m[h] = -3.0e38f; s[h] = 0.f; }
    for (int j = l; j < total; j += 64) {
        const int sid = (j < deg) ? csr[o0 + j] : n;
        const float4 av = *(const float4*)(asrc + sid * 4);
        const float as4[4] = {av.x, av.y, av.z, av.w};
        #pragma unroll
        for (int h = 0; h < 4; ++h) {
            float e = as4[h] + ad[h];
            e = (e > 0.f) ? e : 0.2f * e;
            if (e > m[h]) { s[h] = s[h] * __expf(m[h] - e) + 1.f; m[h] = e; }
            else          { s[h] += __expf(e - m[h]); }
        }
    }
    #pragma unroll
    for (int o = 1; o < 64; o <<= 1) {
        #pragma unroll
        for (int h = 0; h < 4; ++h) {
            const float m2 = __shfl_xor(m[h], o);
            const float s2 = __shfl_xor(s[h], o);
            const float M = fmaxf(m[h], m2);
            const float sa = (s[h] != 0.f) ? s[h] * __expf(m[h] - M) : 0.f;
            const float sb = (s2   != 0.f) ? s2   * __expf(m2   - M) : 0.f;
            m[h] = M; s[h] = sa + sb;
        }
    }
    if (l == 0) {
        #pragma unroll
        for (int h = 0; h < 4; ++h) { mmax[n * 4 + h] = m[h]; den[n * 4 + h] = s[h]; }
    }
}

// ---------------------------------------------------------------------------
// GAT weighted aggregation: bf16 xh gather, bf16 out (+gbias)
// ---------------------------------------------------------------------------
__global__ __launch_bounds__(64)
void k_attn_agg(const unsigned short* __restrict__ xh, const float* __restrict__ asrc,
                const float* __restrict__ adst, const float* __restrict__ mmax,
                const float* __restrict__ den, const float* __restrict__ gbias,
                const int* __restrict__ offs, const int* __restrict__ csr,
                unsigned short* __restrict__ out)
{
    const int n = blockIdx.x;
    const int l = threadIdx.x;
    const int c0 = l * 8;
    const int h = l >> 4;
    const int o0 = offs[n];
    const int deg = offs[n + 1] - o0;
    const int total = deg + 1;
    const float ad = adst[n * 4 + h];
    const float mm = mmax[n * 4 + h];
    const float dn = den[n * 4 + h];
    float acc[8] = {0.f, 0.f, 0.f, 0.f, 0.f, 0.f, 0.f, 0.f};
    for (int j = 0; j < total; ++j) {
        const int sid = (j < deg) ? csr[o0 + j] : n;
        const float4 av = *(const float4*)(asrc + sid * 4);
        const float as4[4] = {av.x, av.y, av.z, av.w};
        float e = as4[h] + ad;
        e = (e > 0.f) ? e : 0.2f * e;
        const float w = __expf(e - mm);
        const uint4 q = *(const uint4*)(xh + (size_t)sid * 512 + c0);
        acc[0] += w * __uint_as_float(q.x << 16);
        acc[1] += w * __uint_as_float(q.x & 0xffff0000u);
        acc[2] += w * __uint_as_float(q.y << 16);
        acc[3] += w * __uint_as_float(q.y & 0xffff0000u);
        acc[4] += w * __uint_as_float(q.z << 16);
        acc[5] += w * __uint_as_float(q.z & 0xffff0000u);
        acc[6] += w * __uint_as_float(q.w << 16);
        acc[7] += w * __uint_as_float(q.w & 0xffff0000u);
    }
    const float r = 1.f / dn;
    float o[8];
    #pragma unroll
    for (int i = 0; i < 8; ++i) o[i] = acc[i] * r + gbias[c0 + i];
    uint4 ov;
    ov.x = pack2(o[0], o[1]); ov.y = pack2(o[2], o[3]);
    ov.z = pack2(o[4], o[5]); ov.w = pack2(o[6], o[7]);
    *(uint4*)(out + (size_t)n * 512 + c0) = ov;
}

// ---------------------------------------------------------------------------
// BatchNorm (training-mode, biased var) + ELU
// ---------------------------------------------------------------------------
__global__ void k_bn_stats_f(const float* __restrict__ X, float* __restrict__ sum,
                             float* __restrict__ sumsq, int C)
{
    const int c = threadIdx.x;
    const int r0 = blockIdx.x * 128;
    const int r1 = min(r0 + 128, NN);
    float s = 0.f, ss = 0.f;
    for (int r = r0; r < r1; ++r) {
        const float v = X[(size_t)r * C + c];
        s += v; ss += v * v;
    }
    atomicAdd(&sum[c], s);
    atomicAdd(&sumsq[c], ss);
}

__global__ void k_bn_stats_b(const unsigned short* __restrict__ X, float* __restrict__ sum,
                             float* __restrict__ sumsq, int C)
{
    const int c = threadIdx.x;
    const int r0 = blockIdx.x * 128;
    const int r1 = min(r0 + 128, NN);
    float s = 0.f, ss = 0.f;
    for (int r = r0; r < r1; ++r) {
        const float v = b2f(X[(size_t)r * C + c]);
        s += v; ss += v * v;
    }
    atomicAdd(&sum[c], s);
    atomicAdd(&sumsq[c], ss);
}

__global__ void k_bn_final(const float* __restrict__ sum, const float* __restrict__ sumsq,
                           const float* __restrict__ g, const float* __restrict__ be,
                           float* __restrict__ scale, float* __restrict__ shift, int C)
{
    const int c = threadIdx.x;
    if (c >= C) return;
    const float mean = sum[c] / (float)NN;
    float var = sumsq[c] / (float)NN - mean * mean;
    var = fmaxf(var, 0.f);
    const float sc = g[c] * rsqrtf(var + BN_EPS);
    scale[c] = sc;
    shift[c] = be[c] - mean * sc;
}

__global__ void k_bn_elu_f2b(const float* __restrict__ X, unsigned short* __restrict__ D,
                             const float* __restrict__ scale, const float* __restrict__ shift,
                             int C, int total)
{
    const int i = blockIdx.x * blockDim.x + threadIdx.x;
    if (i >= total) return;
    const int c = i & (C - 1);
    const float v = X[i] * scale[c] + shift[c];
    D[i] = f2b((v > 0.f) ? v : (__expf(v) - 1.f));
}

__global__ void k_bn_elu_b2b(unsigned short* __restrict__ X,
                             const float* __restrict__ scale, const float* __restrict__ shift,
                             int C, int total)
{
    const int i = blockIdx.x * blockDim.x + threadIdx.x;
    if (i >= total) return;
    const int c = i & (C - 1);
    const float v = b2f(X[i]) * scale[c] + shift[c];
    X[i] = f2b((v > 0.f) ? v : (__expf(v) - 1.f));
}

__global__ void k_bn_elu_f32(float* __restrict__ X,
                             const float* __restrict__ scale, const float* __restrict__ shift,
                             int C, int total)
{
    const int i = blockIdx.x * blockDim.x + threadIdx.x;
    if (i >= total) return;
    const int c = i & (C - 1);
    const float v = X[i] * scale[c] + shift[c];
    X[i] = (v > 0.f) ? v : (__expf(v) - 1.f);
}

// ---------------------------------------------------------------------------
// Final linear: out[n, 0..1] = h4[n,:] @ Wf2^T + bf2
// ---------------------------------------------------------------------------
__global__ void k_fc2(const float* __restrict__ H, const float* __restrict__ W,
                      const float* __restrict__ bias, float* __restrict__ out)
{
    const int n = blockIdx.x * blockDim.x + threadIdx.x;
    if (n >= NN) return;
    float a0 = bias[0], a1 = bias[1];
    const float* h = H + (size_t)n * 64;
    #pragma unroll
    for (int k = 0; k < 64; ++k) {
        const float v = h[k];
        a0 += v * W[k];
        a1 += v * W[64 + k];
    }
    out[n * 2 + 0] = a0;
    out[n * 2 + 1] = a1;
}

// ---------------------------------------------------------------------------
extern "C" void kernel_launch(void* const* d_in, const int* in_sizes, int n_in,
                              void* d_out, int out_size, void* d_ws, size_t ws_size,
                              hipStream_t stream)
{
    const float* x     = (const float*)d_in[0];
    const int*   ei    = (const int*)d_in[1];
    const float* W1l   = (const float*)d_in[2];
    const float* b1    = (const float*)d_in[3];
    const float* W1r   = (const float*)d_in[4];
    const float* g1    = (const float*)d_in[5];
    const float* be1   = (const float*)d_in[6];
    const float* Wg    = (const float*)d_in[7];
    const float* a_s   = (const float*)d_in[8];
    const float* a_d   = (const float*)d_in[9];
    const float* gbias = (const float*)d_in[10];
    const float* g2    = (const float*)d_in[11];
    const float* be2   = (const float*)d_in[12];
    const float* W2l   = (const float*)d_in[13];
    const float* b2    = (const float*)d_in[14];
    const float* W2r   = (const float*)d_in[15];
    const float* g3    = (const float*)d_in[16];
    const float* be3   = (const float*)d_in[17];
    const float* Wf1   = (const float*)d_in[18];
    const float* bf1   = (const float*)d_in[19];
    const float* g4    = (const float*)d_in[20];
    const float* be4   = (const float*)d_in[21];
    const float* Wf2   = (const float*)d_in[22];
    const float* bf2   = (const float*)d_in[23];
    const int* src = ei;
    const int* dst = ei + EE;

    char* ws = (char*)d_ws;
    size_t off = 0;
    auto alloc = [&](size_t bytes) -> char* {
        char* p = ws + off;
        off += (bytes + 255) & ~(size_t)255;
        return p;
    };
    unsigned short* xb   = (unsigned short*)alloc((size_t)NN * 256 * 2);
    unsigned short* waren= (unsigned short*)alloc(270336 * 2);
    unsigned short* tlb  = (unsigned short*)alloc((size_t)NN * 128 * 2);
    float*          trF  = (float*)alloc((size_t)NN * 128 * 4);
    unsigned short* h1b  = (unsigned short*)alloc((size_t)NN * 128 * 2);
    unsigned short* xhb  = (unsigned short*)alloc((size_t)NN * 512 * 2);
    unsigned short* gatb = (unsigned short*)alloc((size_t)NN * 512 * 2);
    float* asrc  = (float*)alloc((size_t)NN * 4 * 4);
    float* adst  = (float*)alloc((size_t)NN * 4 * 4);
    float* mmax  = (float*)alloc((size_t)NN * 4 * 4);
    float* den   = (float*)alloc((size_t)NN * 4 * 4);
    float* stats = (float*)alloc(2048 * 4);
    int*   cnt   = (int*)alloc((size_t)NN * 4);
    int*   offs  = (int*)alloc((size_t)(NN + 1) * 4);
    int*   fill  = (int*)alloc((size_t)NN * 4);
    int*   csr   = (int*)alloc((size_t)EE * 4);
    int*   bsum  = (int*)alloc((size_t)NB_SCAN * 4);
    if (off > ws_size) return;
    (void)in_sizes; (void)n_in; (void)out_size;

    unsigned short* W1l_b = waren;
    unsigned short* W1r_b = waren + 32768;
    unsigned short* Wg_b  = waren + 65536;
    unsigned short* W2l_b = waren + 131072;
    unsigned short* W2r_b = waren + 196608;
    unsigned short* Wf1_b = waren + 262144;

    float* sum   = stats;
    float* sumsq = stats + 512;
    float* scale = stats + 1024;
    float* shift = stats + 1536;

    // ---- converts + CSR build ----
    k_conv_x<<<6250, 256, 0, stream>>>(x, xb);
    k_conv_w<<<1056, 256, 0, stream>>>(W1l, W1r, Wg, W2l, W2r, Wf1, waren);
    hipMemsetAsync(cnt, 0, (size_t)NN * 4, stream);
    hipMemsetAsync(fill, 0, (size_t)NN * 4, stream);
    k_count<<<(EE + 255) / 256, 256, 0, stream>>>(dst, cnt);
    k_scan_blk<<<NB_SCAN, 256, 0, stream>>>(cnt, offs, bsum, NN);
    k_scan_top<<<1, 256, 0, stream>>>(bsum, offs, NN);
    k_scan_add<<<NB_SCAN, 256, 0, stream>>>(offs, bsum, NN);
    k_fill<<<(EE + 255) / 256, 256, 0, stream>>>(src, dst, offs, fill, csr);

    const int gy = (NN + 127) / 128;   // 391

    // ---- Layer 1: SAGE(256 -> 128) + BN + ELU ----
    gemm_bf16mm<1><<<dim3(1, gy), 256, 0, stream>>>(xb, W1l_b, nullptr, tlb, NN, 256, 128);
    gemm_bf16mm<0><<<dim3(1, gy), 256, 0, stream>>>(xb, W1r_b, nullptr, trF, NN, 256, 128);
    k_sage_agg<<<NN, 128, 0, stream>>>(tlb, trF, b1, offs, csr);
    hipMemsetAsync(sum, 0, 1024 * 4, stream);
    k_bn_stats_f<<<gy, 128, 0, stream>>>(trF, sum, sumsq, 128);
    k_bn_final<<<1, 128, 0, stream>>>(sum, sumsq, g1, be1, scale, shift, 128);
    k_bn_elu_f2b<<<(NN * 128 + 255) / 256, 256, 0, stream>>>(trF, h1b, scale, shift, 128, NN * 128);

    // ---- Layer 2: GAT(128 -> 4x128) + BN + ELU ----
    gemm_bf16mm<1><<<dim3(4, gy), 256, 0, stream>>>(h1b, Wg_b, nullptr, xhb, NN, 128, 512);
    k_attn_coef<<<NN, 64, 0, stream>>>(xhb, a_s, a_d, asrc, adst);
    k_attn_mdn<<<NN, 64, 0, stream>>>(asrc, adst, offs, csr, mmax, den);
    k_attn_agg<<<NN, 64, 0, stream>>>(xhb, asrc, adst, mmax, den, gbias, offs, csr, gatb);
    hipMemsetAsync(sum, 0, 1024 * 4, stream);
    k_bn_stats_b<<<gy, 512, 0, stream>>>(gatb, sum, sumsq, 512);
    k_bn_final<<<1, 512, 0, stream>>>(sum, sumsq, g2, be2, scale, shift, 512);
    k_bn_elu_b2b<<<(NN * 512 + 255) / 256, 256, 0, stream>>>(gatb, scale, shift, 512, NN * 512);

    // ---- Layer 3: SAGE(512 -> 128) + BN + ELU ----
    gemm_bf16mm<1><<<dim3(1, gy), 256, 0, stream>>>(gatb, W2l_b, nullptr, tlb, NN, 512, 128);
    gemm_bf16mm<0><<<dim3(1, gy), 256, 0, stream>>>(gatb, W2r_b, nullptr, trF, NN, 512, 128);
    k_sage_agg<<<NN, 128, 0, stream>>>(tlb, trF, b2, offs, csr);
    hipMemsetAsync(sum, 0, 1024 * 4, stream);
    k_bn_stats_f<<<gy, 128, 0, stream>>>(trF, sum, sumsq, 128);
    k_bn_final<<<1, 128, 0, stream>>>(sum, sumsq, g3, be3, scale, shift, 128);
    k_bn_elu_f2b<<<(NN * 128 + 255) / 256, 256, 0, stream>>>(trF, h1b, scale, shift, 128, NN * 128);

    // ---- Layer 4: Linear(128 -> 64) + BN + ELU ----
    gemm_bf16mm<0><<<dim3(1, gy), 256, 0, stream>>>(h1b, Wf1_b, bf1, trF, NN, 128, 64);
    hipMemsetAsync(sum, 0, 1024 * 4, stream);
    k_bn_stats_f<<<gy, 64, 0, stream>>>(trF, sum, sumsq, 64);
    k_bn_final<<<1, 64, 0, stream>>>(sum, sumsq, g4, be4, scale, shift, 64);
    k_bn_elu_f32<<<(NN * 64 + 255) / 256, 256, 0, stream>>>(trF, scale, shift, 64, NN * 64);

    // ---- Layer 5: Linear(64 -> 2) ----
    k_fc2<<<(NN + 255) / 256, 256, 0, stream>>>(trF, Wf2, bf2, (float*)d_out);
}

// Round 4
// 707.968 us; speedup vs baseline: 1.8516x; 1.1365x over previous
//
#include <hip/hip_runtime.h>
#include <cstdint>
#include <cstddef>

#define NN 50000
#define EE 400000
#define BN_EPS 1e-5f
#define NB_SCAN 196   // ceil(50000/256)

typedef __attribute__((ext_vector_type(8))) short s16x8;
typedef __attribute__((ext_vector_type(4))) float floatx4;

// bf16 helpers (raw ushort storage, RNE rounding)
__device__ __forceinline__ unsigned short f2b(float f) {
    uint32_t u = __float_as_uint(f);
    uint32_t r = (u + 0x7fffu + ((u >> 16) & 1u)) >> 16;
    return (unsigned short)r;
}
__device__ __forceinline__ float b2f(unsigned short s) {
    return __uint_as_float((uint32_t)s << 16);
}
__device__ __forceinline__ uint32_t pack2(float a, float b) {
    return (uint32_t)f2b(a) | ((uint32_t)f2b(b) << 16);
}
__device__ __forceinline__ float b2f_lo(uint32_t u) { return __uint_as_float(u << 16); }
__device__ __forceinline__ float b2f_hi(uint32_t u) { return __uint_as_float(u & 0xffff0000u); }

#define GLD16(g, l) __builtin_amdgcn_global_load_lds(                          \
    (const __attribute__((address_space(1))) uint32_t*)(g),                    \
    (__attribute__((address_space(3))) uint32_t*)(l), 16, 0, 0)

// ---------------------------------------------------------------------------
// bf16 MFMA GEMM (NT) with split epilogue:
//   col c < split  -> Cb[r*ldb + c]            (bf16)
//   col c >= split -> Cf[r*ldf + (c-split)]    (f32, + bias[c-split] if bias)
// BM=BN=128, BK=32, 256 threads = 4 waves, mfma_f32_16x16x32_bf16, K%32==0.
// ---------------------------------------------------------------------------
__global__ __launch_bounds__(256)
void gemm_bf16mm(const unsigned short* __restrict__ A,
                 const unsigned short* __restrict__ W,
                 const float* __restrict__ bias,
                 unsigned short* __restrict__ Cb, float* __restrict__ Cf,
                 int split, int M, int K, int Ncol, int ldb, int ldf)
{
    __shared__ __align__(16) unsigned short As[128 * 32];
    __shared__ __align__(16) unsigned short Bs[128 * 32];
    const int t  = threadIdx.x;
    const int m0 = blockIdx.y * 128;
    const int n0 = blockIdx.x * 128;
    const int lane = t & 63;
    const int lr = lane & 15;
    const int lq = lane >> 4;
    const int wr = (t >> 7) * 64;
    const int wc = ((t >> 6) & 1) * 64;

    floatx4 acc[4][4];
    const floatx4 zero = {0.f, 0.f, 0.f, 0.f};
    #pragma unroll
    for (int i = 0; i < 4; ++i)
        #pragma unroll
        for (int j = 0; j < 4; ++j) acc[i][j] = zero;

    for (int k0 = 0; k0 < K; k0 += 32) {
        #pragma unroll
        for (int it = 0; it < 2; ++it) {
            const int seg = t + it * 256;
            const int row = seg >> 2;
            const int ks  = (seg & 3) * 8;
            const unsigned short* ga = A + (size_t)min(m0 + row, M - 1) * K + k0 + ks;
            GLD16(ga, As + seg * 8);
            const unsigned short* gb = W + (size_t)min(n0 + row, Ncol - 1) * K + k0 + ks;
            GLD16(gb, Bs + seg * 8);
        }
        __syncthreads();

        s16x8 af[4], bf[4];
        #pragma unroll
        for (int i = 0; i < 4; ++i) {
            af[i] = *(const s16x8*)(As + (wr + i * 16 + lr) * 32 + lq * 8);
            bf[i] = *(const s16x8*)(Bs + (wc + i * 16 + lr) * 32 + lq * 8);
        }
        #pragma unroll
        for (int i = 0; i < 4; ++i)
            #pragma unroll
            for (int j = 0; j < 4; ++j)
                acc[i][j] = __builtin_amdgcn_mfma_f32_16x16x32_bf16(
                    af[i], bf[j], acc[i][j], 0, 0, 0);
        __syncthreads();
    }

    #pragma unroll
    for (int i = 0; i < 4; ++i) {
        #pragma unroll
        for (int j = 0; j < 4; ++j) {
            const int c = n0 + wc + j * 16 + lr;
            if (c >= Ncol) continue;
            #pragma unroll
            for (int r4 = 0; r4 < 4; ++r4) {
                const int r = m0 + wr + i * 16 + lq * 4 + r4;
                if (r < M) {
                    const float v = acc[i][j][r4];
                    if (c < split) {
                        Cb[(size_t)r * ldb + c] = f2b(v);
                    } else {
                        const int cc = c - split;
                        Cf[(size_t)r * ldf + cc] = v + (bias ? bias[cc] : 0.f);
                    }
                }
            }
        }
    }
}

// ---------------------------------------------------------------------------
// fp32 -> bf16 converts
// ---------------------------------------------------------------------------
__global__ void k_conv_x(const float* __restrict__ x, unsigned short* __restrict__ xb)
{
    const int i8 = (blockIdx.x * 256 + threadIdx.x) * 8;
    const float4 f0 = *(const float4*)(x + i8);
    const float4 f1 = *(const float4*)(x + i8 + 4);
    uint4 o;
    o.x = pack2(f0.x, f0.y); o.y = pack2(f0.z, f0.w);
    o.z = pack2(f1.x, f1.y); o.w = pack2(f1.z, f1.w);
    *(uint4*)(xb + i8) = o;
}

__global__ void k_conv_w(const float* __restrict__ s0, const float* __restrict__ s1,
                         const float* __restrict__ s2, const float* __restrict__ s3,
                         const float* __restrict__ s4, const float* __restrict__ s5,
                         unsigned short* __restrict__ dst)
{
    const int i = blockIdx.x * 256 + threadIdx.x;
    if (i >= 270336) return;
    float v;
    if      (i < 32768)  v = s0[i];
    else if (i < 65536)  v = s1[i - 32768];
    else if (i < 131072) v = s2[i - 65536];
    else if (i < 196608) v = s3[i - 131072];
    else if (i < 262144) v = s4[i - 196608];
    else                 v = s5[i - 262144];
    dst[i] = f2b(v);
}

// ---------------------------------------------------------------------------
// CSR build: count -> multi-block exclusive scan -> fill
// ---------------------------------------------------------------------------
__global__ void k_count(const int* __restrict__ dst, int* __restrict__ cnt)
{
    int i = blockIdx.x * blockDim.x + threadIdx.x;
    if (i < EE) atomicAdd(&cnt[dst[i]], 1);
}

__global__ __launch_bounds__(256)
void k_scan_blk(const int* __restrict__ cnt, int* __restrict__ offs,
                int* __restrict__ bsum, int N)
{
    __shared__ int wsum[4];
    const int t = threadIdx.x;
    const int i = blockIdx.x * 256 + t;
    const int v = (i < N) ? cnt[i] : 0;
    int s = v;
    #pragma unroll
    for (int o = 1; o < 64; o <<= 1) {
        const int u = __shfl_up(s, o);
        if ((t & 63) >= o) s += u;
    }
    const int wid = t >> 6;
    if ((t & 63) == 63) wsum[wid] = s;
    __syncthreads();
    int base = 0;
    #pragma unroll
    for (int w = 0; w < 3; ++w) if (w < wid) base += wsum[w];
    if (i < N) offs[i] = base + s - v;
    if (t == 255) bsum[blockIdx.x] = base + s;
}

__global__ __launch_bounds__(256)
void k_scan_top(int* __restrict__ bsum, int* __restrict__ offs, int N)
{
    __shared__ int wsum[4];
    const int t = threadIdx.x;
    const int v = (t < NB_SCAN) ? bsum[t] : 0;
    int s = v;
    #pragma unroll
    for (int o = 1; o < 64; o <<= 1) {
        const int u = __shfl_up(s, o);
        if ((t & 63) >= o) s += u;
    }
    const int wid = t >> 6;
    if ((t & 63) == 63) wsum[wid] = s;
    __syncthreads();
    int base = 0;
    #pragma unroll
    for (int w = 0; w < 3; ++w) if (w < wid) base += wsum[w];
    if (t < NB_SCAN) bsum[t] = base + s - v;
    if (t == 255) offs[N] = base + s;
}

__global__ __launch_bounds__(256)
void k_scan_add(int* __restrict__ offs, const int* __restrict__ bsum, int N)
{
    const int i = blockIdx.x * 256 + threadIdx.x;
    if (i < N) offs[i] += bsum[blockIdx.x];
}

__global__ void k_fill(const int* __restrict__ src, const int* __restrict__ dst,
                       const int* __restrict__ offs, int* __restrict__ fill,
                       int* __restrict__ csr)
{
    int i = blockIdx.x * blockDim.x + threadIdx.x;
    if (i < EE) {
        int d = dst[i];
        int p = offs[d] + atomicAdd(&fill[d], 1);
        csr[p] = src[i];
    }
}

// ---------------------------------------------------------------------------
// SAGE aggregation: one wave per node, uint (2ch) loads -> 256B/edge/wave
// tr[n] = mean_{s in in(n)} tl_b[s] + bias + tr[n]
// ---------------------------------------------------------------------------
__global__ __launch_bounds__(64)
void k_sage_agg(const unsigned short* __restrict__ tl, float* __restrict__ tr,
                const float* __restrict__ bias, const int* __restrict__ offs,
                const int* __restrict__ csr)
{
    const int n = blockIdx.x;
    const int l = threadIdx.x;
    const int o0 = offs[n], o1 = offs[n + 1];
    const int deg = o1 - o0;
    float a0 = 0.f, a1 = 0.f;
    for (int j = o0; j < o1; ++j) {
        const int sid = csr[j];
        const uint32_t u = *(const uint32_t*)(tl + (size_t)sid * 128 + l * 2);
        a0 += b2f_lo(u);
        a1 += b2f_hi(u);
    }
    const float inv = 1.f / fmaxf((float)deg, 1.f);
    const float2 bv = *(const float2*)(bias + l * 2);
    float2* trp = (float2*)(tr + (size_t)n * 128) + l;
    float2 v = *trp;
    v.x += a0 * inv + bv.x;
    v.y += a1 * inv + bv.y;
    *trp = v;
}

// ---------------------------------------------------------------------------
// GAT per-node coefficients
// ---------------------------------------------------------------------------
__global__ __launch_bounds__(64)
void k_attn_coef(const unsigned short* __restrict__ xh, const float* __restrict__ a_s,
                 const float* __restrict__ a_d, float* __restrict__ asrc,
                 float* __restrict__ adst)
{
    const int n = blockIdx.x;
    const int l = threadIdx.x;
    const int c0 = l * 8;
    const int h = l >> 4;
    const uint4 q = *(const uint4*)(xh + (size_t)n * 512 + c0);
    float v[8];
    v[0] = b2f_lo(q.x); v[1] = b2f_hi(q.x);
    v[2] = b2f_lo(q.y); v[3] = b2f_hi(q.y);
    v[4] = b2f_lo(q.z); v[5] = b2f_hi(q.z);
    v[6] = b2f_lo(q.w); v[7] = b2f_hi(q.w);
    float ps = 0.f, pd = 0.f;
    #pragma unroll
    for (int i = 0; i < 8; ++i) {
        ps += v[i] * a_s[c0 + i];
        pd += v[i] * a_d[c0 + i];
    }
    #pragma unroll
    for (int o = 1; o < 16; o <<= 1) {
        ps += __shfl_xor(ps, o);
        pd += __shfl_xor(pd, o);
    }
    if ((l & 15) == 0) { asrc[n * 4 + h] = ps; adst[n * 4 + h] = pd; }
}

// ---------------------------------------------------------------------------
// GAT fused: online softmax (pass 1) + weighted aggregation (pass 2)
// one wave per node
// ---------------------------------------------------------------------------
__global__ __launch_bounds__(64)
void k_attn_fused(const unsigned short* __restrict__ xh, const float* __restrict__ asrc,
                  const float* __restrict__ adst, const float* __restrict__ gbias,
                  const int* __restrict__ offs, const int* __restrict__ csr,
                  unsigned short* __restrict__ out)
{
    const int n = blockIdx.x;
    const int l = threadIdx.x;
    const int o0 = offs[n];
    const int deg = offs[n + 1] - o0;
    const int total = deg + 1;                  // + self loop
    const float4 adv = *(const float4*)(adst + n * 4);
    const float ad4[4] = {adv.x, adv.y, adv.z, adv.w};

    // ---- pass 1: per-head max + denominator (online) ----
    float m[4], s[4];
    #pragma unroll
    for (int h = 0; h < 4; ++h) { m[h] = -3.0e38f; s[h] = 0.f; }
    for (int j = l; j < total; j += 64) {
        const int sid = (j < deg) ? csr[o0 + j] : n;
        const float4 av = *(const float4*)(asrc + sid * 4);
        const float as4[4] = {av.x, av.y, av.z, av.w};
        #pragma unroll
        for (int h = 0; h < 4; ++h) {
            float e = as4[h] + ad4[h];
            e = (e > 0.f) ? e : 0.2f * e;
            if (e > m[h]) { s[h] = s[h] * __expf(m[h] - e) + 1.f; m[h] = e; }
            else          { s[h] += __expf(e - m[h]); }
        }
    }
    #pragma unroll
    for (int o = 1; o < 64; o <<= 1) {
        #pragma unroll
        for (int h = 0; h < 4; ++h) {
            const float m2 = __shfl_xor(m[h], o);
            const float s2 = __shfl_xor(s[h], o);
            const float M = fmaxf(m[h], m2);
            const float sa = (s[h] != 0.f) ? s[h] * __expf(m[h] - M) : 0.f;
            const float sb = (s2   != 0.f) ? s2   * __expf(m2   - M) : 0.f;
            m[h] = M; s[h] = sa + sb;
        }
    }

    // ---- pass 2: weighted gather over this lane's 8 channels ----
    const int c0 = l * 8;
    const int h = l >> 4;
    const float ad = ad4[h];
    const float mm = m[h];
    const float dn = s[h];
    float acc[8] = {0.f, 0.f, 0.f, 0.f, 0.f, 0.f, 0.f, 0.f};
    for (int j = 0; j < total; ++j) {
        const int sid = (j < deg) ? csr[o0 + j] : n;
        const float4 av = *(const float4*)(asrc + sid * 4);
        const float as4[4] = {av.x, av.y, av.z, av.w};
        float e = as4[h] + ad;
        e = (e > 0.f) ? e : 0.2f * e;
        const float w = __expf(e - mm);
        const uint4 q = *(const uint4*)(xh + (size_t)sid * 512 + c0);
        acc[0] += w * b2f_lo(q.x); acc[1] += w * b2f_hi(q.x);
        acc[2] += w * b2f_lo(q.y); acc[3] += w * b2f_hi(q.y);
        acc[4] += w * b2f_lo(q.z); acc[5] += w * b2f_hi(q.z);
        acc[6] += w * b2f_lo(q.w); acc[7] += w * b2f_hi(q.w);
    }
    const float r = 1.f / dn;
    float o[8];
    #pragma unroll
    for (int i = 0; i < 8; ++i) o[i] = acc[i] * r + gbias[c0 + i];
    uint4 ov;
    ov.x = pack2(o[0], o[1]); ov.y = pack2(o[2], o[3]);
    ov.z = pack2(o[4], o[5]); ov.w = pack2(o[6], o[7]);
    *(uint4*)(out + (size_t)n * 512 + c0) = ov;
}

// ---------------------------------------------------------------------------
// BatchNorm (training-mode, biased var) + ELU
// ---------------------------------------------------------------------------
// fp32, C=64: block 64, scalar
__global__ void k_bn_stats_f(const float* __restrict__ X, float* __restrict__ sum,
                             float* __restrict__ sumsq, int C)
{
    const int c = threadIdx.x;
    const int r0 = blockIdx.x * 128;
    const int r1 = min(r0 + 128, NN);
    float s = 0.f, ss = 0.f;
    for (int r = r0; r < r1; ++r) {
        const float v = X[(size_t)r * C + c];
        s += v; ss += v * v;
    }
    atomicAdd(&sum[c], s);
    atomicAdd(&sumsq[c], ss);
}

// fp32, C=128: block 64, float2 per thread
__global__ void k_bn_stats_f2(const float* __restrict__ X, float* __restrict__ sum,
                              float* __restrict__ sumsq)
{
    const int c = threadIdx.x * 2;
    const int r0 = blockIdx.x * 128;
    const int r1 = min(r0 + 128, NN);
    float s0 = 0.f, s1 = 0.f, q0 = 0.f, q1 = 0.f;
    for (int r = r0; r < r1; ++r) {
        const float2 v = *(const float2*)(X + (size_t)r * 128 + c);
        s0 += v.x; q0 += v.x * v.x;
        s1 += v.y; q1 += v.y * v.y;
    }
    atomicAdd(&sum[c], s0);   atomicAdd(&sum[c + 1], s1);
    atomicAdd(&sumsq[c], q0); atomicAdd(&sumsq[c + 1], q1);
}

// bf16, C=512: block 256, uint (2ch) per thread
__global__ void k_bn_stats_b2(const unsigned short* __restrict__ X, float* __restrict__ sum,
                              float* __restrict__ sumsq)
{
    const int c = threadIdx.x * 2;
    const int r0 = blockIdx.x * 128;
    const int r1 = min(r0 + 128, NN);
    float s0 = 0.f, s1 = 0.f, q0 = 0.f, q1 = 0.f;
    for (int r = r0; r < r1; ++r) {
        const uint32_t u = *(const uint32_t*)(X + (size_t)r * 512 + c);
        const float v0 = b2f_lo(u), v1 = b2f_hi(u);
        s0 += v0; q0 += v0 * v0;
        s1 += v1; q1 += v1 * v1;
    }
    atomicAdd(&sum[c], s0);   atomicAdd(&sum[c + 1], s1);
    atomicAdd(&sumsq[c], q0); atomicAdd(&sumsq[c + 1], q1);
}

__global__ void k_bn_final(const float* __restrict__ sum, const float* __restrict__ sumsq,
                           const float* __restrict__ g, const float* __restrict__ be,
                           float* __restrict__ scale, float* __restrict__ shift, int C)
{
    const int c = threadIdx.x;
    if (c >= C) return;
    const float mean = sum[c] / (float)NN;
    float var = sumsq[c] / (float)NN - mean * mean;
    var = fmaxf(var, 0.f);
    const float sc = g[c] * rsqrtf(var + BN_EPS);
    scale[c] = sc;
    shift[c] = be[c] - mean * sc;
}

// fp32 in -> bf16 out, 4 elems/thread
__global__ void k_bn_elu_f2b(const float* __restrict__ X, unsigned short* __restrict__ D,
                             const float* __restrict__ scale, const float* __restrict__ shift,
                             int Cm1, int total)
{
    const int i = (blockIdx.x * 256 + threadIdx.x) * 4;
    if (i >= total) return;
    const int c = i & Cm1;
    const float4 x = *(const float4*)(X + i);
    float o[4] = {x.x, x.y, x.z, x.w};
    #pragma unroll
    for (int k = 0; k < 4; ++k) {
        const float v = o[k] * scale[c + k] + shift[c + k];
        o[k] = (v > 0.f) ? v : (__expf(v) - 1.f);
    }
    uint2 ov;
    ov.x = pack2(o[0], o[1]); ov.y = pack2(o[2], o[3]);
    *(uint2*)(D + i) = ov;
}

// bf16 in-place, 4 elems/thread
__global__ void k_bn_elu_b2b(unsigned short* __restrict__ X,
                             const float* __restrict__ scale, const float* __restrict__ shift,
                             int Cm1, int total)
{
    const int i = (blockIdx.x * 256 + threadIdx.x) * 4;
    if (i >= total) return;
    const int c = i & Cm1;
    const uint2 u = *(const uint2*)(X + i);
    float o[4] = {b2f_lo(u.x), b2f_hi(u.x), b2f_lo(u.y), b2f_hi(u.y)};
    #pragma unroll
    for (int k = 0; k < 4; ++k) {
        const float v = o[k] * scale[c + k] + shift[c + k];
        o[k] = (v > 0.f) ? v : (__expf(v) - 1.f);
    }
    uint2 ov;
    ov.x = pack2(o[0], o[1]); ov.y = pack2(o[2], o[3]);
    *(uint2*)(X + i) = ov;
}

// ---------------------------------------------------------------------------
// Fused layer-4 BN+ELU + final linear: one wave per node
// ---------------------------------------------------------------------------
__global__ __launch_bounds__(64)
void k_bn_elu_fc2(const float* __restrict__ X, const float* __restrict__ scale,
                  const float* __restrict__ shift, const float* __restrict__ W,
                  const float* __restrict__ bias, float* __restrict__ out)
{
    const int n = blockIdx.x;
    const int c = threadIdx.x;
    float v = X[(size_t)n * 64 + c] * scale[c] + shift[c];
    v = (v > 0.f) ? v : (__expf(v) - 1.f);
    float p0 = v * W[c];
    float p1 = v * W[64 + c];
    #pragma unroll
    for (int o = 1; o < 64; o <<= 1) {
        p0 += __shfl_xor(p0, o);
        p1 += __shfl_xor(p1, o);
    }
    if (c == 0) {
        out[n * 2 + 0] = p0 + bias[0];
        out[n * 2 + 1] = p1 + bias[1];
    }
}

// ---------------------------------------------------------------------------
extern "C" void kernel_launch(void* const* d_in, const int* in_sizes, int n_in,
                              void* d_out, int out_size, void* d_ws, size_t ws_size,
                              hipStream_t stream)
{
    const float* x     = (const float*)d_in[0];
    const int*   ei    = (const int*)d_in[1];
    const float* W1l   = (const float*)d_in[2];
    const float* b1    = (const float*)d_in[3];
    const float* W1r   = (const float*)d_in[4];
    const float* g1    = (const float*)d_in[5];
    const float* be1   = (const float*)d_in[6];
    const float* Wg    = (const float*)d_in[7];
    const float* a_s   = (const float*)d_in[8];
    const float* a_d   = (const float*)d_in[9];
    const float* gbias = (const float*)d_in[10];
    const float* g2    = (const float*)d_in[11];
    const float* be2   = (const float*)d_in[12];
    const float* W2l   = (const float*)d_in[13];
    const float* b2    = (const float*)d_in[14];
    const float* W2r   = (const float*)d_in[15];
    const float* g3    = (const float*)d_in[16];
    const float* be3   = (const float*)d_in[17];
    const float* Wf1   = (const float*)d_in[18];
    const float* bf1   = (const float*)d_in[19];
    const float* g4    = (const float*)d_in[20];
    const float* be4   = (const float*)d_in[21];
    const float* Wf2   = (const float*)d_in[22];
    const float* bf2   = (const float*)d_in[23];
    const int* src = ei;
    const int* dst = ei + EE;

    char* ws = (char*)d_ws;
    size_t off = 0;
    auto alloc = [&](size_t bytes) -> char* {
        char* p = ws + off;
        off += (bytes + 255) & ~(size_t)255;
        return p;
    };
    unsigned short* xb   = (unsigned short*)alloc((size_t)NN * 256 * 2);
    unsigned short* waren= (unsigned short*)alloc(270336 * 2);
    unsigned short* tlb  = (unsigned short*)alloc((size_t)NN * 128 * 2);
    float*          trF  = (float*)alloc((size_t)NN * 128 * 4);
    unsigned short* h1b  = (unsigned short*)alloc((size_t)NN * 128 * 2);
    unsigned short* xhb  = (unsigned short*)alloc((size_t)NN * 512 * 2);
    unsigned short* gatb = (unsigned short*)alloc((size_t)NN * 512 * 2);
    float* asrc  = (float*)alloc((size_t)NN * 4 * 4);
    float* adst  = (float*)alloc((size_t)NN * 4 * 4);
    float* stats = (float*)alloc(2048 * 4);
    int*   cnt   = (int*)alloc((size_t)NN * 4);
    int*   offs  = (int*)alloc((size_t)(NN + 1) * 4);
    int*   fill  = (int*)alloc((size_t)NN * 4);
    int*   csr   = (int*)alloc((size_t)EE * 4);
    int*   bsum  = (int*)alloc((size_t)NB_SCAN * 4);
    if (off > ws_size) return;
    (void)in_sizes; (void)n_in; (void)out_size;

    unsigned short* W1cat = waren;            // W1l || W1r : 256 rows x 256
    unsigned short* Wg_b  = waren + 65536;    // 512 x 128
    unsigned short* W2cat = waren + 131072;   // W2l || W2r : 256 rows x 512
    unsigned short* Wf1_b = waren + 262144;   // 64 x 128

    float* sum   = stats;
    float* sumsq = stats + 512;
    float* scale = stats + 1024;
    float* shift = stats + 1536;

    // ---- converts + CSR build ----
    k_conv_x<<<6250, 256, 0, stream>>>(x, xb);
    k_conv_w<<<1056, 256, 0, stream>>>(W1l, W1r, Wg, W2l, W2r, Wf1, waren);
    hipMemsetAsync(cnt, 0, (size_t)NN * 4, stream);
    hipMemsetAsync(fill, 0, (size_t)NN * 4, stream);
    k_count<<<(EE + 255) / 256, 256, 0, stream>>>(dst, cnt);
    k_scan_blk<<<NB_SCAN, 256, 0, stream>>>(cnt, offs, bsum, NN);
    k_scan_top<<<1, 256, 0, stream>>>(bsum, offs, NN);
    k_scan_add<<<NB_SCAN, 256, 0, stream>>>(offs, bsum, NN);
    k_fill<<<(EE + 255) / 256, 256, 0, stream>>>(src, dst, offs, fill, csr);

    const int gy = (NN + 127) / 128;   // 391

    // ---- Layer 1: SAGE(256 -> 128) + BN + ELU ----
    // merged: cols 0-127 = W1l (tl, bf16) ; cols 128-255 = W1r (tr, f32)
    gemm_bf16mm<<<dim3(2, gy), 256, 0, stream>>>(xb, W1cat, nullptr, tlb, trF,
                                                 128, NN, 256, 256, 128, 128);
    k_sage_agg<<<NN, 64, 0, stream>>>(tlb, trF, b1, offs, csr);
    hipMemsetAsync(sum, 0, 1024 * 4, stream);
    k_bn_stats_f2<<<gy, 64, 0, stream>>>(trF, sum, sumsq);
    k_bn_final<<<1, 128, 0, stream>>>(sum, sumsq, g1, be1, scale, shift, 128);
    k_bn_elu_f2b<<<(NN * 128 / 4 + 255) / 256, 256, 0, stream>>>(trF, h1b, scale, shift, 127, NN * 128);

    // ---- Layer 2: GAT(128 -> 4x128) + BN + ELU ----
    gemm_bf16mm<<<dim3(4, gy), 256, 0, stream>>>(h1b, Wg_b, nullptr, xhb, nullptr,
                                                 512, NN, 128, 512, 512, 0);
    k_attn_coef<<<NN, 64, 0, stream>>>(xhb, a_s, a_d, asrc, adst);
    k_attn_fused<<<NN, 64, 0, stream>>>(xhb, asrc, adst, gbias, offs, csr, gatb);
    hipMemsetAsync(sum, 0, 1024 * 4, stream);
    k_bn_stats_b2<<<gy, 256, 0, stream>>>(gatb, sum, sumsq);
    k_bn_final<<<1, 512, 0, stream>>>(sum, sumsq, g2, be2, scale, shift, 512);
    k_bn_elu_b2b<<<(NN * 512 / 4 + 255) / 256, 256, 0, stream>>>(gatb, scale, shift, 511, NN * 512);

    // ---- Layer 3: SAGE(512 -> 128) + BN + ELU ----
    gemm_bf16mm<<<dim3(2, gy), 256, 0, stream>>>(gatb, W2cat, nullptr, tlb, trF,
                                                 128, NN, 512, 256, 128, 128);
    k_sage_agg<<<NN, 64, 0, stream>>>(tlb, trF, b2, offs, csr);
    hipMemsetAsync(sum, 0, 1024 * 4, stream);
    k_bn_stats_f2<<<gy, 64, 0, stream>>>(trF, sum, sumsq);
    k_bn_final<<<1, 128, 0, stream>>>(sum, sumsq, g3, be3, scale, shift, 128);
    k_bn_elu_f2b<<<(NN * 128 / 4 + 255) / 256, 256, 0, stream>>>(trF, h1b, scale, shift, 127, NN * 128);

    // ---- Layer 4: Linear(128 -> 64) + BN ----
    gemm_bf16mm<<<dim3(1, gy), 256, 0, stream>>>(h1b, Wf1_b, bf1, nullptr, trF,
                                                 0, NN, 128, 64, 0, 64);
    hipMemsetAsync(sum, 0, 1024 * 4, stream);
    k_bn_stats_f<<<gy, 64, 0, stream>>>(trF, sum, sumsq, 64);
    k_bn_final<<<1, 64, 0, stream>>>(sum, sumsq, g4, be4, scale, shift, 64);

    // ---- Layer 4 ELU + Layer 5 Linear(64 -> 2), fused ----
    k_bn_elu_fc2<<<NN, 64, 0, stream>>>(trF, scale, shift, Wf2, bf2, (float*)d_out);
}